// Round 5
// baseline (288.164 us; speedup 1.0000x reference)
//
#include <hip/hip_runtime.h>
#include <hip/hip_bf16.h>

#define N_ATOMS 10000
#define N_PAIRS 100000
#define HH 64
#define MAXZ 100

typedef _Float16 h2_t __attribute__((ext_vector_type(2)));

constexpr float RBF_START = 0.6065306597126334f;
constexpr float RBF_STEP  = (1.0f - RBF_START) / 31.0f;
constexpr float RBF_BETA  = 1.0f / ((0.0625f * (1.0f - RBF_START)) * (0.0625f * (1.0f - RBF_START)));
constexpr float LOG2E     = 1.4426950408889634f;
constexpr float NEG_ALPHA_L2 = -10.0f * LOG2E;
constexpr float NEG_BETA_L2  = -RBF_BETA * LOG2E;

// ---- f32 param layout in workspace (element offsets) ----
#define OFF_EMB   0
#define OFF_W2    6400
#define OFF_B2    14592
#define OFF_D1W   14656
#define OFF_D1B   16704
#define OFF_D2W   16768
#define OFF_D2B   18816
#define OFF_D3W   18880
#define OFF_D3B   20928
#define OFF_LT0   20992
#define OFF_LT1   25088
#define OFF_LT2   29184
#define OFF_L1W   33280
#define OFF_L1B   41472
#define OFF_L2W   41600
#define OFF_L2B   66176
#define OFF_LNG   66368
#define OFF_LNB   66432
#define N_PARAMF  66496

// packed-half (uint) region layout inside PH
#define PH_DP   0        // 3 x 64 x 16 uints
#define PH_L1   3072     // 128 x 32
#define PH_L2   7168     // 192 x 64
#define PH_LT   19456    // 3 x 64 x 32
#define PH_N    25600

// ws byte offsets
#define WS_WF     0
#define WS_CNT    266240
#define WS_OFF    307200
#define WS_CUR    348160
#define WS_T1     389120
#define WS_T2     414720
#define WS_PH     440320
#define WS_DPK    542720
#define WS_ZNL    2142720

__device__ __forceinline__ float bf2f(unsigned short u) {
    return __uint_as_float(((unsigned int)u) << 16);
}
__device__ __forceinline__ float fexp2(float x) { return __builtin_amdgcn_exp2f(x); }
__device__ __forceinline__ float fcos2pi(float x) { return __builtin_amdgcn_cosf(x); }
__device__ __forceinline__ float fsilu(float x) { return x / (1.0f + fexp2(-LOG2E * x)); }
__device__ __forceinline__ h2_t u2h(unsigned u) { return __builtin_bit_cast(h2_t, u); }
__device__ __forceinline__ unsigned packh2(float a, float b) {
    h2_t v; v.x = (_Float16)a; v.y = (_Float16)b;
    return __builtin_bit_cast(unsigned, v);
}

#if __has_builtin(__builtin_amdgcn_fdot2)
__device__ __forceinline__ float FDOT2(h2_t a, h2_t b, float c) {
    return __builtin_amdgcn_fdot2(a, b, c, false);
}
#else
__device__ __forceinline__ float FDOT2(h2_t a, h2_t b, float c) {
    return c + (float)a.x * (float)b.x + (float)a.y * (float)b.y;
}
#endif
__device__ __forceinline__ float dot16h(const uint4* w, const uint4* x, float acc) {
    uint4 a = *w, b = *x;
    acc = FDOT2(u2h(a.x), u2h(b.x), acc);
    acc = FDOT2(u2h(a.y), u2h(b.y), acc);
    acc = FDOT2(u2h(a.z), u2h(b.z), acc);
    acc = FDOT2(u2h(a.w), u2h(b.w), acc);
    return acc;
}
__device__ __forceinline__ float dot16v(uint4 a, uint4 b, float acc) {
    acc = FDOT2(u2h(a.x), u2h(b.x), acc);
    acc = FDOT2(u2h(a.y), u2h(b.y), acc);
    acc = FDOT2(u2h(a.z), u2h(b.z), acc);
    acc = FDOT2(u2h(a.w), u2h(b.w), acc);
    return acc;
}

// ---- buffer layout probe: 1 = u16/bf16 array, 0 = f32 ----
__device__ int classify64(const unsigned short* b, int lane) {
    unsigned short x = b[lane];
    int e = (x >> 7) & 0xFF;
    bool implaus = (x != 0) && (e < 96 || e > 133);
    bool zeroeven = ((lane & 1) == 0) && (x == 0);
    unsigned long long mi = __ballot(implaus);
    unsigned long long mz = __ballot(zeroeven);
    if (__popcll(mz) == 32) return 0;
    if (__popcll(mi) >= 8) return 0;
    return 1;
}

__device__ __forceinline__ float ldp(const void* p, int off, int fl) {
    if (fl == 1) return bf2f(((const unsigned short*)p)[off]);
    return ((const float*)p)[off];
}

struct ConvArgs { const void* src[18]; float* dst; };

// Fused: params->f32 WF + pair counting (blocks 0..390) | T1/T2 + fp16 packing
// from RAW inputs (blocks 391..490).
__global__ void k_prep(ConvArgs a, const int* __restrict__ pidx, int* __restrict__ cnt,
                       float* __restrict__ T1, float* __restrict__ T2,
                       unsigned* __restrict__ PH) {
    const int sizes[18] = {6400,8192,64,2048,64,2048,64,2048,64,4096,4096,4096,8192,128,24576,192,64,64};
    __shared__ int fl;
    if (threadIdx.x < 64) {
        int f = classify64((const unsigned short*)a.src[0], threadIdx.x);
        if (threadIdx.x == 0) fl = f;
    }
    __syncthreads();

    if (blockIdx.x < 391) {
        int t = blockIdx.x * 256 + threadIdx.x;
        if (t < N_PARAMF) {
            int acc = 0, seg = 0, off = t;
            #pragma unroll
            for (int i = 0; i < 18; ++i) {
                if (t >= acc && t < acc + sizes[i]) { seg = i; off = t - acc; }
                acc += sizes[i];
            }
            a.dst[t] = ldp(a.src[seg], off, fl);
        }
        if (t < N_PAIRS) atomicAdd(&cnt[pidx[t]], 1);
        return;
    }

    // ---- tabpack blocks ----
    int zb = blockIdx.x - 391;            // 0..99
    int h = threadIdx.x;
    if (h < 64) {
        float s1 = 0.f, s2 = 0.f;
        #pragma unroll
        for (int k = 0; k < 64; ++k) {
            float e = ldp(a.src[0], zb * HH + k, fl);          // emb[z][k]
            s1 += ldp(a.src[1], h * 128 + k, fl) * e;          // emb2_w rows
            s2 += ldp(a.src[1], h * 128 + 64 + k, fl) * e;
        }
        T1[zb * HH + h] = s1;
        T2[zb * HH + h] = s2;
    }
    int q = zb * 256 + threadIdx.x;       // 0..25599
    const void* sp; int off;
    if (q < PH_L1) {
        int w = q >> 10, r = q & 1023;
        sp = a.src[3 + 2 * w];            // dp1_w / dp2_w / dp3_w
        off = r * 2;
    } else if (q < PH_L2) {
        sp = a.src[12]; off = (q - PH_L1) * 2;                 // ls1_w
    } else if (q < PH_LT) {
        sp = a.src[14]; off = (q - PH_L2) * 2;                 // ls2_w
    } else {
        int tt = q - PH_LT;
        sp = a.src[9 + (tt >> 11)]; off = (tt & 2047) * 2;     // lt0/lt1/lt2
    }
    PH[q] = packh2(ldp(sp, off, fl), ldp(sp, off + 1, fl));
}

// shfl-based scan: wave-scan (6 shfl) + 16 wave partials, 1 barrier.
__global__ void k_scan(const int* __restrict__ cnt, int* __restrict__ offs, int* __restrict__ cur) {
    __shared__ int wsum[16];
    int tid = threadIdx.x;                // 0..1023
    int lane = tid & 63, wid = tid >> 6;
    int base = tid * 10;
    int c[10]; int s = 0;
    #pragma unroll
    for (int i = 0; i < 10; ++i) {
        int idx = base + i;
        int v = (idx < N_ATOMS) ? cnt[idx] : 0;
        c[i] = v; s += v;
    }
    int inc = s;
    #pragma unroll
    for (int o = 1; o < 64; o <<= 1) {
        int v = __shfl_up(inc, o);
        if (lane >= o) inc += v;
    }
    if (lane == 63) wsum[wid] = inc;
    __syncthreads();
    int wbase = 0;
    #pragma unroll
    for (int w = 0; w < 16; ++w) {
        int v = wsum[w];
        if (w < wid) wbase += v;
    }
    int run = wbase + (inc - s);          // exclusive prefix for this thread
    #pragma unroll
    for (int i = 0; i < 10; ++i) {
        int idx = base + i;
        if (idx < N_ATOMS) { offs[idx] = run; cur[idx] = run; run += c[i]; }
    }
    if (tid == 0) offs[N_ATOMS] = N_PAIRS;
}

__global__ void k_fill(const int* __restrict__ pidx, const int* __restrict__ an,
                       const void* __restrict__ dij_v, const void* __restrict__ rij_v,
                       int* __restrict__ cur,
                       float4* __restrict__ dpack, int* __restrict__ znl) {
    __shared__ int fdr[2];
    if (threadIdx.x < 64) {
        int fd = classify64((const unsigned short*)dij_v, threadIdx.x);
        int fr = classify64((const unsigned short*)rij_v, threadIdx.x);
        if (threadIdx.x == 0) { fdr[0] = fd; fdr[1] = fr; }
    }
    __syncthreads();
    int p = blockIdx.x * 256 + threadIdx.x;
    if (p >= N_PAIRS) return;
    int s = pidx[p];
    int dst = pidx[N_PAIRS + p];
    int pos = atomicAdd(&cur[s], 1);
    float d, rx, ry, rz;
    if (fdr[0] == 1) d = bf2f(((const unsigned short*)dij_v)[p]);
    else             d = ((const float*)dij_v)[p];
    if (fdr[1] == 1) {
        const unsigned short* r = (const unsigned short*)rij_v;
        rx = bf2f(r[3*p]); ry = bf2f(r[3*p+1]); rz = bf2f(r[3*p+2]);
    } else {
        const float* r = (const float*)rij_v;
        rx = r[3*p]; ry = r[3*p+1]; rz = r[3*p+2];
    }
    dpack[pos] = make_float4(rx, ry, rz, d);
    znl[pos] = an[dst];
}

// FUSED pair accumulation + epilogue. 4 waves/block, 1 atom/wave, 2500 blocks.
// VGPR-tier history (counters):
//   (256,2): VGPR 88, clean loop, k_pair 110us @ 19% occ (LDS-capped, round 2)
//   (256,5): VGPR 48, scratch spill (FETCH+4.6MB WRITE+14.5MB), 161us (round 3)
//   (256,4): VGPR 64, no spill but weight-hoist rematerialized in-loop from
//            L1/L2 (VALUBusy 31->23%, slower than round 2 at HIGHER occ), 147us
// => the 64-reg tier poisons the loop; the natural ~88-reg build is clean.
// This round: (256,2) budget (no pressure) + small LDS (9KB). HW occupancy is
// set by ACTUAL usage: ~88-96 VGPR -> 5 waves/SIMD -> up to 20 waves/CU.
__global__ __launch_bounds__(256, 2) void k_pair(
    const int* __restrict__ an,
    const float* __restrict__ WF,
    const int* __restrict__ offs,
    const float4* __restrict__ dpack, const int* __restrict__ znl,
    const float* __restrict__ T1, const float* __restrict__ T2,
    const unsigned* __restrict__ PH,
    float* __restrict__ out)
{
    __shared__ __align__(16) unsigned rbq[4 * 16];
    __shared__ __align__(16) unsigned acch[4][12 * 32];
    __shared__ __align__(16) unsigned y1h[4][64];
    __shared__ __align__(16) unsigned y2h[4][96];

    const int wave = threadIdx.x >> 6;
    const int h    = threadIdx.x & 63;
    const int n    = blockIdx.x * 4 + wave;

    _Float16* rbfh = (_Float16*)&rbq[wave * 16];
    const uint4* rbp = (const uint4*)&rbq[wave * 16];

    // hoist per-lane dp weight rows into registers
    const uint4* g1 = (const uint4*)(PH + PH_DP + 0 * 1024 + h * 16);
    const uint4* g2 = (const uint4*)(PH + PH_DP + 1 * 1024 + h * 16);
    const uint4* g3 = (const uint4*)(PH + PH_DP + 2 * 1024 + h * 16);
    uint4 w1r[4], w2r[4], w3r[4];
    #pragma unroll
    for (int k = 0; k < 4; ++k) {
        w1r[k] = g1[k];
        w2r[k] = g2[k];
        w3r[k] = g3[k];
    }

    const float ed1 = (WF + OFF_D1B)[h];
    const float ed2 = (WF + OFF_D2B)[h];
    const float ed3 = (WF + OFF_D3B)[h];
    const float zA  = (WF + OFF_B2)[h] + T1[an[n] * HH + h];

    float Is=0.f, sx=0.f, sy=0.f, sz=0.f;
    float Sxx=0.f, Syy=0.f, Szz=0.f, Sxy=0.f, Sxz=0.f, Syz=0.f;

    const int pbeg = offs[n], pend = offs[n + 1];

    // software pipeline: dpack 2-ahead, T2 1-ahead, znl 2-ahead
    float4 dp_cur = make_float4(0.f, 0.f, 0.f, 1.f);
    float4 dp_nxt = make_float4(0.f, 0.f, 0.f, 1.f);
    float  t2cur  = 0.f;
    int    zn_n   = 0;
    if (pbeg < pend) {
        dp_cur = dpack[pbeg];
        t2cur  = T2[znl[pbeg] * HH + h];
        if (pbeg + 1 < pend) {
            dp_nxt = dpack[pbeg + 1];
            zn_n   = znl[pbeg + 1];
        }
    }

    for (int ii = pbeg; ii < pend; ++ii) {
        const float4 dpv = dp_cur;
        const float  t2v = t2cur;
        dp_cur = dp_nxt;
        if (ii + 2 < pend) dp_nxt = dpack[ii + 2];
        if (ii + 1 < pend) t2cur  = T2[zn_n * HH + h];
        if (ii + 2 < pend) zn_n   = znl[ii + 2];

        float d = dpv.w;
        float inv = 1.0f / d;
        float ux = dpv.x*inv, uy = dpv.y*inv, uz = dpv.z*inv;
        float rc = (d < 0.5f) ? 0.5f * (fcos2pi(d) + 1.0f) : 0.0f;

        if (h < 32) {
            float en = fexp2(NEG_ALPHA_L2 * d);
            float t = en - (RBF_START + RBF_STEP * (float)h);
            rbfh[h] = (_Float16)(fexp2(NEG_BETA_L2 * t * t) * rc);
        }
        __builtin_amdgcn_wave_barrier();

        float g1a = ed1, g2a = ed2, g3a = ed3;
        #pragma unroll
        for (int k = 0; k < 4; ++k) {
            uint4 rb = rbp[k];
            g1a = dot16v(w1r[k], rb, g1a);
            g2a = dot16v(w2r[k], rb, g2a);
            g3a = dot16v(w3r[k], rb, g3a);
        }

        float zc = zA + t2v;
        float Cc = rc * zc;
        float f1 = g1a * Cc;
        float f2 = g2a * Cc * 10.0f;
        float f3 = g3a * Cc * 100.0f;

        Is += f1;
        sx += f2 * ux;  sy += f2 * uy;  sz += f2 * uz;
        float q = (ux*ux + uy*uy + uz*uz) * (1.0f / 3.0f);
        Sxx += f3 * (ux*ux - q);
        Syy += f3 * (uy*uy - q);
        Szz += f3 * (uz*uz - q);
        Sxy += f3 * (ux*uy);
        Sxz += f3 * (ux*uz);
        Syz += f3 * (uy*uz);
        __builtin_amdgcn_wave_barrier();
    }

    // tn + LayerNorm (f32, before any fp16 rounding)
    float tn = 3.0f*Is*Is + 2.0f*(sx*sx + sy*sy + sz*sz)
             + Sxx*Sxx + Syy*Syy + Szz*Szz
             + 2.0f*(Sxy*Sxy + Sxz*Sxz + Syz*Syz);
    float s1 = tn, s2 = tn * tn;
    #pragma unroll
    for (int o = 32; o > 0; o >>= 1) {
        s1 += __shfl_xor(s1, o);
        s2 += __shfl_xor(s2, o);
    }
    float mu  = s1 * (1.0f / 64.0f);
    float var = s2 * (1.0f / 64.0f) - mu * mu;
    float nv  = (tn - mu) * rsqrtf(var + 1e-5f) * (WF + OFF_LNG)[h] + (WF + OFF_LNB)[h];

    // pack 11 vectors (10 accums + nv) to fp16 pairs into per-wave LDS
    float vals[11] = {Is, sx, sy, sz, Sxx, Syy, Szz, Sxy, Sxz, Syz, nv};
    #pragma unroll
    for (int c = 0; c < 11; ++c) {
        float pv = __shfl_xor(vals[c], 1);
        if ((h & 1) == 0)
            acch[wave][c * 32 + (h >> 1)] = packh2(vals[c], pv);
    }
    __builtin_amdgcn_wave_barrier();

    const uint4* nvh = (const uint4*)&acch[wave][10 * 32];
    const uint4* l1base = (const uint4*)(PH + PH_L1);

    // y1 = silu(ls1_w @ nv + b1): j = h, h+64
    float ya = (WF + OFF_L1B)[h];
    float yb = (WF + OFF_L1B)[h + 64];
    {
        const uint4* ra = l1base + h * 8;
        const uint4* rb = l1base + (h + 64) * 8;
        #pragma unroll
        for (int k = 0; k < 8; ++k) {
            ya = dot16h(ra + k, nvh + k, ya);
            yb = dot16h(rb + k, nvh + k, yb);
        }
    }
    ya = fsilu(ya); yb = fsilu(yb);
    {
        float pa = __shfl_xor(ya, 1);
        float pb = __shfl_xor(yb, 1);
        if ((h & 1) == 0) {
            y1h[wave][(h >> 1)]      = packh2(ya, pa);
            y1h[wave][32 + (h >> 1)] = packh2(yb, pb);
        }
    }
    __builtin_amdgcn_wave_barrier();

    // y2 = silu(ls2_w @ y1 + b2): m = h, h+64, h+128 (ls2 rows from GLOBAL/L2)
    const uint4* y1p = (const uint4*)&y1h[wave][0];
    float z0 = (WF + OFF_L2B)[h];
    float z1 = (WF + OFF_L2B)[h + 64];
    float z2 = (WF + OFF_L2B)[h + 128];
    {
        const uint4* l2base = (const uint4*)(PH + PH_L2);
        const uint4* r0 = l2base + (h)       * 16;
        const uint4* r1 = l2base + (h + 64)  * 16;
        const uint4* r2 = l2base + (h + 128) * 16;
        #pragma unroll
        for (int k = 0; k < 16; ++k) {
            uint4 x = y1p[k];
            uint4 a0 = r0[k], a1 = r1[k], a2 = r2[k];
            z0 = FDOT2(u2h(a0.x), u2h(x.x), z0); z0 = FDOT2(u2h(a0.y), u2h(x.y), z0);
            z0 = FDOT2(u2h(a0.z), u2h(x.z), z0); z0 = FDOT2(u2h(a0.w), u2h(x.w), z0);
            z1 = FDOT2(u2h(a1.x), u2h(x.x), z1); z1 = FDOT2(u2h(a1.y), u2h(x.y), z1);
            z1 = FDOT2(u2h(a1.z), u2h(x.z), z1); z1 = FDOT2(u2h(a1.w), u2h(x.w), z1);
            z2 = FDOT2(u2h(a2.x), u2h(x.x), z2); z2 = FDOT2(u2h(a2.y), u2h(x.y), z2);
            z2 = FDOT2(u2h(a2.z), u2h(x.z), z2); z2 = FDOT2(u2h(a2.w), u2h(x.w), z2);
        }
    }
    z0 = fsilu(z0); z1 = fsilu(z1); z2 = fsilu(z2);
    {
        float p0 = __shfl_xor(z0, 1);
        float p1 = __shfl_xor(z1, 1);
        float p2 = __shfl_xor(z2, 1);
        if ((h & 1) == 0) {
            y2h[wave][(h >> 1)]      = packh2(z0, p0);
            y2h[wave][32 + (h >> 1)] = packh2(z1, p1);
            y2h[wave][64 + (h >> 1)] = packh2(z2, p2);
        }
    }
    __builtin_amdgcn_wave_barrier();

    // norm multipliers n0..n2 = y2[3h..3h+2]
    float n0, n1, n2;
    {
        int i0 = 3 * h;
        unsigned u0 = y2h[wave][i0 >> 1];
        unsigned u1 = y2h[wave][(i0 >> 1) + 1];
        h2_t aa = u2h(u0), bb = u2h(u1);
        if (i0 & 1) { n0 = (float)aa.y; n1 = (float)bb.x; n2 = (float)bb.y; }
        else        { n0 = (float)aa.x; n1 = (float)aa.y; n2 = (float)bb.x; }
    }

    // transform: 10 dot64 against lt rows (global, L2-resident)
    const uint4* lt0 = (const uint4*)(PH + PH_LT) + h * 8;
    const uint4* lt1 = (const uint4*)(PH + PH_LT + 2048) + h * 8;
    const uint4* lt2 = (const uint4*)(PH + PH_LT + 4096) + h * 8;

    const uint4* aI  = (const uint4*)&acch[wave][0];
    const uint4* aAx = (const uint4*)&acch[wave][32];
    const uint4* aAy = (const uint4*)&acch[wave][64];
    const uint4* aAz = (const uint4*)&acch[wave][96];
    const uint4* aXX = (const uint4*)&acch[wave][128];
    const uint4* aYY = (const uint4*)&acch[wave][160];
    const uint4* aZZ = (const uint4*)&acch[wave][192];
    const uint4* aXY = (const uint4*)&acch[wave][224];
    const uint4* aXZ = (const uint4*)&acch[wave][256];
    const uint4* aYZ = (const uint4*)&acch[wave][288];

    float P0=0.f, PAx=0.f, PAy=0.f, PAz=0.f;
    float Q0=0.f, Q1=0.f, Q2=0.f, Q3=0.f, Q4=0.f, Q5=0.f;
    #pragma unroll
    for (int k = 0; k < 8; ++k) {
        P0  = dot16h(lt0 + k, aI  + k, P0);
        PAx = dot16h(lt1 + k, aAx + k, PAx);
        PAy = dot16h(lt1 + k, aAy + k, PAy);
        PAz = dot16h(lt1 + k, aAz + k, PAz);
        Q0  = dot16h(lt2 + k, aXX + k, Q0);
        Q1  = dot16h(lt2 + k, aYY + k, Q1);
        Q2  = dot16h(lt2 + k, aZZ + k, Q2);
        Q3  = dot16h(lt2 + k, aXY + k, Q3);
        Q4  = dot16h(lt2 + k, aXZ + k, Q4);
        Q5  = dot16h(lt2 + k, aYZ + k, Q5);
    }
    float Iv = P0 * n0;
    float Ax = PAx * n1, Ay = PAy * n1, Az = PAz * n1;
    float Xx = Q0 * n2, Yy = Q1 * n2, Zz = Q2 * n2;
    float Xy = Q3 * n2, Xz = Q4 * n2, Yz = Q5 * n2;

    float* o = out + (size_t)n * 576 + h * 9;
    o[0] =  Iv + Xx;  o[1] = -Az + Xy;  o[2] =  Ay + Xz;
    o[3] =  Az + Xy;  o[4] =  Iv + Yy;  o[5] = -Ax + Yz;
    o[6] = -Ay + Xz;  o[7] =  Ax + Yz;  o[8] =  Iv + Zz;
}

extern "C" void kernel_launch(void* const* d_in, const int* in_sizes, int n_in,
                              void* d_out, int out_size, void* d_ws, size_t ws_size,
                              hipStream_t stream) {
    const int* an   = (const int*)d_in[0];
    const int* pidx = (const int*)d_in[1];

    char* ws = (char*)d_ws;
    float*    WF    = (float*)(ws + WS_WF);
    int*      cnt   = (int*)(ws + WS_CNT);
    int*      offs  = (int*)(ws + WS_OFF);
    int*      cur   = (int*)(ws + WS_CUR);
    float*    T1    = (float*)(ws + WS_T1);
    float*    T2    = (float*)(ws + WS_T2);
    unsigned* PH    = (unsigned*)(ws + WS_PH);
    float4*   dpack = (float4*)(ws + WS_DPK);
    int*      znl   = (int*)(ws + WS_ZNL);
    float*    out   = (float*)d_out;

    hipMemsetAsync(cnt, 0, N_ATOMS * sizeof(int), stream);

    ConvArgs ca;
    for (int i = 0; i < 18; ++i) ca.src[i] = d_in[4 + i];
    ca.dst = WF;
    k_prep<<<491, 256, 0, stream>>>(ca, pidx, cnt, T1, T2, PH);
    k_scan<<<1, 1024, 0, stream>>>(cnt, offs, cur);
    k_fill<<<(N_PAIRS + 255) / 256, 256, 0, stream>>>(pidx, an, d_in[2], d_in[3],
                                                      cur, dpack, znl);
    k_pair<<<2500, 256, 0, stream>>>(an, WF, offs, dpack, znl, T1, T2, PH, out);
}

// Round 6
// 235.752 us; speedup vs baseline: 1.2223x; 1.2223x over previous
//
#include <hip/hip_runtime.h>
#include <hip/hip_bf16.h>

#define N_ATOMS 10000
#define N_PAIRS 100000
#define HH 64
#define MAXZ 100

typedef _Float16 h2_t __attribute__((ext_vector_type(2)));

constexpr float RBF_START = 0.6065306597126334f;
constexpr float RBF_STEP  = (1.0f - RBF_START) / 31.0f;
constexpr float RBF_BETA  = 1.0f / ((0.0625f * (1.0f - RBF_START)) * (0.0625f * (1.0f - RBF_START)));
constexpr float LOG2E     = 1.4426950408889634f;
constexpr float NEG_ALPHA_L2 = -10.0f * LOG2E;
constexpr float NEG_BETA_L2  = -RBF_BETA * LOG2E;

// ---- f32 param layout in workspace (element offsets) ----
#define OFF_EMB   0
#define OFF_W2    6400
#define OFF_B2    14592
#define OFF_D1W   14656
#define OFF_D1B   16704
#define OFF_D2W   16768
#define OFF_D2B   18816
#define OFF_D3W   18880
#define OFF_D3B   20928
#define OFF_LT0   20992
#define OFF_LT1   25088
#define OFF_LT2   29184
#define OFF_L1W   33280
#define OFF_L1B   41472
#define OFF_L2W   41600
#define OFF_L2B   66176
#define OFF_LNG   66368
#define OFF_LNB   66432
#define N_PARAMF  66496

// packed-half (uint) region layout inside PH
#define PH_DP   0        // 3 x 64 x 16 uints
#define PH_L1   3072     // 128 x 32
#define PH_L2   7168     // 192 x 64
#define PH_LT   19456    // 3 x 64 x 32
#define PH_N    25600

// ws byte offsets
#define WS_WF     0
#define WS_CNT    266240
#define WS_OFF    307200
#define WS_CUR    348160
#define WS_T1     389120
#define WS_T2     414720
#define WS_PH     440320
#define WS_DPK    542720
#define WS_ZNL    2142720
#define WS_ACCH   2542720   // 10000 x 11 x 32 uints = 14.08 MB

__device__ __forceinline__ float bf2f(unsigned short u) {
    return __uint_as_float(((unsigned int)u) << 16);
}
__device__ __forceinline__ float fexp2(float x) { return __builtin_amdgcn_exp2f(x); }
__device__ __forceinline__ float fcos2pi(float x) { return __builtin_amdgcn_cosf(x); }
__device__ __forceinline__ float fsilu(float x) { return x / (1.0f + fexp2(-LOG2E * x)); }
__device__ __forceinline__ h2_t u2h(unsigned u) { return __builtin_bit_cast(h2_t, u); }
__device__ __forceinline__ unsigned packh2(float a, float b) {
    h2_t v; v.x = (_Float16)a; v.y = (_Float16)b;
    return __builtin_bit_cast(unsigned, v);
}

#if __has_builtin(__builtin_amdgcn_fdot2)
__device__ __forceinline__ float FDOT2(h2_t a, h2_t b, float c) {
    return __builtin_amdgcn_fdot2(a, b, c, false);
}
#else
__device__ __forceinline__ float FDOT2(h2_t a, h2_t b, float c) {
    return c + (float)a.x * (float)b.x + (float)a.y * (float)b.y;
}
#endif
__device__ __forceinline__ float dot16h(const uint4* w, const uint4* x, float acc) {
    uint4 a = *w, b = *x;
    acc = FDOT2(u2h(a.x), u2h(b.x), acc);
    acc = FDOT2(u2h(a.y), u2h(b.y), acc);
    acc = FDOT2(u2h(a.z), u2h(b.z), acc);
    acc = FDOT2(u2h(a.w), u2h(b.w), acc);
    return acc;
}

// ---- buffer layout probe: 1 = u16/bf16 array, 0 = f32 ----
__device__ int classify64(const unsigned short* b, int lane) {
    unsigned short x = b[lane];
    int e = (x >> 7) & 0xFF;
    bool implaus = (x != 0) && (e < 96 || e > 133);
    bool zeroeven = ((lane & 1) == 0) && (x == 0);
    unsigned long long mi = __ballot(implaus);
    unsigned long long mz = __ballot(zeroeven);
    if (__popcll(mz) == 32) return 0;
    if (__popcll(mi) >= 8) return 0;
    return 1;
}

__device__ __forceinline__ float ldp(const void* p, int off, int fl) {
    if (fl == 1) return bf2f(((const unsigned short*)p)[off]);
    return ((const float*)p)[off];
}

struct ConvArgs { const void* src[18]; float* dst; };

// Fused: params->f32 WF + pair counting (blocks 0..390) | T1/T2 + fp16 packing
// from RAW inputs (blocks 391..490).
__global__ void k_prep(ConvArgs a, const int* __restrict__ pidx, int* __restrict__ cnt,
                       float* __restrict__ T1, float* __restrict__ T2,
                       unsigned* __restrict__ PH) {
    const int sizes[18] = {6400,8192,64,2048,64,2048,64,2048,64,4096,4096,4096,8192,128,24576,192,64,64};
    __shared__ int fl;
    if (threadIdx.x < 64) {
        int f = classify64((const unsigned short*)a.src[0], threadIdx.x);
        if (threadIdx.x == 0) fl = f;
    }
    __syncthreads();

    if (blockIdx.x < 391) {
        int t = blockIdx.x * 256 + threadIdx.x;
        if (t < N_PARAMF) {
            int acc = 0, seg = 0, off = t;
            #pragma unroll
            for (int i = 0; i < 18; ++i) {
                if (t >= acc && t < acc + sizes[i]) { seg = i; off = t - acc; }
                acc += sizes[i];
            }
            a.dst[t] = ldp(a.src[seg], off, fl);
        }
        if (t < N_PAIRS) atomicAdd(&cnt[pidx[t]], 1);
        return;
    }

    // ---- tabpack blocks ----
    int zb = blockIdx.x - 391;            // 0..99
    int h = threadIdx.x;
    if (h < 64) {
        float s1 = 0.f, s2 = 0.f;
        #pragma unroll
        for (int k = 0; k < 64; ++k) {
            float e = ldp(a.src[0], zb * HH + k, fl);          // emb[z][k]
            s1 += ldp(a.src[1], h * 128 + k, fl) * e;          // emb2_w rows
            s2 += ldp(a.src[1], h * 128 + 64 + k, fl) * e;
        }
        T1[zb * HH + h] = s1;
        T2[zb * HH + h] = s2;
    }
    int q = zb * 256 + threadIdx.x;       // 0..25599
    const void* sp; int off;
    if (q < PH_L1) {
        int w = q >> 10, r = q & 1023;
        sp = a.src[3 + 2 * w];            // dp1_w / dp2_w / dp3_w
        off = r * 2;
    } else if (q < PH_L2) {
        sp = a.src[12]; off = (q - PH_L1) * 2;                 // ls1_w
    } else if (q < PH_LT) {
        sp = a.src[14]; off = (q - PH_L2) * 2;                 // ls2_w
    } else {
        int tt = q - PH_LT;
        sp = a.src[9 + (tt >> 11)]; off = (tt & 2047) * 2;     // lt0/lt1/lt2
    }
    PH[q] = packh2(ldp(sp, off, fl), ldp(sp, off + 1, fl));
}

// shfl-based scan: wave-scan (6 shfl) + 16 wave partials, 1 barrier.
__global__ void k_scan(const int* __restrict__ cnt, int* __restrict__ offs, int* __restrict__ cur) {
    __shared__ int wsum[16];
    int tid = threadIdx.x;                // 0..1023
    int lane = tid & 63, wid = tid >> 6;
    int base = tid * 10;
    int c[10]; int s = 0;
    #pragma unroll
    for (int i = 0; i < 10; ++i) {
        int idx = base + i;
        int v = (idx < N_ATOMS) ? cnt[idx] : 0;
        c[i] = v; s += v;
    }
    int inc = s;
    #pragma unroll
    for (int o = 1; o < 64; o <<= 1) {
        int v = __shfl_up(inc, o);
        if (lane >= o) inc += v;
    }
    if (lane == 63) wsum[wid] = inc;
    __syncthreads();
    int wbase = 0;
    #pragma unroll
    for (int w = 0; w < 16; ++w) {
        int v = wsum[w];
        if (w < wid) wbase += v;
    }
    int run = wbase + (inc - s);          // exclusive prefix for this thread
    #pragma unroll
    for (int i = 0; i < 10; ++i) {
        int idx = base + i;
        if (idx < N_ATOMS) { offs[idx] = run; cur[idx] = run; run += c[i]; }
    }
    if (tid == 0) offs[N_ATOMS] = N_PAIRS;
}

__global__ void k_fill(const int* __restrict__ pidx, const int* __restrict__ an,
                       const void* __restrict__ dij_v, const void* __restrict__ rij_v,
                       int* __restrict__ cur,
                       float4* __restrict__ dpack, int* __restrict__ znl) {
    __shared__ int fdr[2];
    if (threadIdx.x < 64) {
        int fd = classify64((const unsigned short*)dij_v, threadIdx.x);
        int fr = classify64((const unsigned short*)rij_v, threadIdx.x);
        if (threadIdx.x == 0) { fdr[0] = fd; fdr[1] = fr; }
    }
    __syncthreads();
    int p = blockIdx.x * 256 + threadIdx.x;
    if (p >= N_PAIRS) return;
    int s = pidx[p];
    int dst = pidx[N_PAIRS + p];
    int pos = atomicAdd(&cur[s], 1);
    float d, rx, ry, rz;
    if (fdr[0] == 1) d = bf2f(((const unsigned short*)dij_v)[p]);
    else             d = ((const float*)dij_v)[p];
    if (fdr[1] == 1) {
        const unsigned short* r = (const unsigned short*)rij_v;
        rx = bf2f(r[3*p]); ry = bf2f(r[3*p+1]); rz = bf2f(r[3*p+2]);
    } else {
        const float* r = (const float*)rij_v;
        rx = r[3*p]; ry = r[3*p+1]; rz = r[3*p+2];
    }
    dpack[pos] = make_float4(rx, ry, rz, d);
    znl[pos] = an[dst];
}

// Pair accumulation (SPLIT again: rounds 2-5 proved fusion costs 50-90us vs
// the split round-1 structure). 4 waves/block, 1 atom/wave, 2500 blocks.
// New this round:
//  - ZERO LDS, zero barriers: rbf is computed by ALL lanes (h&31), packed via
//    shfl_down, then broadcast to uniform regs via 16x v_readlane. Replaces the
//    per-iteration LDS round-trip (~120cyc serial latency) with pure VALU.
//  - dp weight hoist pinned with asm keep-alives so the compiler cannot sink
//    the loads into the loop (rounds 4/5 failure mode: VGPR tier 64/68 ->
//    rematerialized loads, VALUBusy collapse).
__global__ __launch_bounds__(256, 2) void k_pair(
    const int* __restrict__ an,
    const float* __restrict__ WF,
    const int* __restrict__ offs,
    const float4* __restrict__ dpack, const int* __restrict__ znl,
    const float* __restrict__ T1, const float* __restrict__ T2,
    const unsigned* __restrict__ PH,
    unsigned* __restrict__ accH)
{
    const int wave = threadIdx.x >> 6;
    const int h    = threadIdx.x & 63;
    const int n    = blockIdx.x * 4 + wave;

    // hoist per-lane dp weight rows (48 scalars) into registers, pinned
    unsigned w1u[16], w2u[16], w3u[16];
    {
        const uint4* g1 = (const uint4*)(PH + PH_DP + 0 * 1024 + h * 16);
        const uint4* g2 = (const uint4*)(PH + PH_DP + 1 * 1024 + h * 16);
        const uint4* g3 = (const uint4*)(PH + PH_DP + 2 * 1024 + h * 16);
        #pragma unroll
        for (int k = 0; k < 4; ++k) {
            uint4 a = g1[k]; w1u[4*k] = a.x; w1u[4*k+1] = a.y; w1u[4*k+2] = a.z; w1u[4*k+3] = a.w;
            uint4 b = g2[k]; w2u[4*k] = b.x; w2u[4*k+1] = b.y; w2u[4*k+2] = b.z; w2u[4*k+3] = b.w;
            uint4 c = g3[k]; w3u[4*k] = c.x; w3u[4*k+1] = c.y; w3u[4*k+2] = c.z; w3u[4*k+3] = c.w;
        }
    }
    #pragma unroll
    for (int q = 0; q < 16; ++q)
        asm volatile("" : "+v"(w1u[q]), "+v"(w2u[q]), "+v"(w3u[q]));

    const float ed1 = (WF + OFF_D1B)[h];
    const float ed2 = (WF + OFF_D2B)[h];
    const float ed3 = (WF + OFF_D3B)[h];
    const float zA  = (WF + OFF_B2)[h] + T1[an[n] * HH + h];

    float Is=0.f, sx=0.f, sy=0.f, sz=0.f;
    float Sxx=0.f, Syy=0.f, Szz=0.f, Sxy=0.f, Sxz=0.f, Syz=0.f;

    const int pbeg = offs[n], pend = offs[n + 1];

    const float meanj = RBF_START + RBF_STEP * (float)(h & 31);

    // software pipeline: dpack 2-ahead, T2 1-ahead, znl 2-ahead
    float4 dp_cur = make_float4(0.f, 0.f, 0.f, 1.f);
    float4 dp_nxt = make_float4(0.f, 0.f, 0.f, 1.f);
    float  t2cur  = 0.f;
    int    zn_n   = 0;
    if (pbeg < pend) {
        dp_cur = dpack[pbeg];
        t2cur  = T2[znl[pbeg] * HH + h];
        if (pbeg + 1 < pend) {
            dp_nxt = dpack[pbeg + 1];
            zn_n   = znl[pbeg + 1];
        }
    }

    for (int ii = pbeg; ii < pend; ++ii) {
        const float4 dpv = dp_cur;
        const float  t2v = t2cur;
        dp_cur = dp_nxt;
        if (ii + 2 < pend) dp_nxt = dpack[ii + 2];
        if (ii + 1 < pend) t2cur  = T2[zn_n * HH + h];
        if (ii + 2 < pend) zn_n   = znl[ii + 2];

        float d = dpv.w;
        float inv = 1.0f / d;
        float ux = dpv.x*inv, uy = dpv.y*inv, uz = dpv.z*inv;
        float rc = (d < 0.5f) ? 0.5f * (fcos2pi(d) + 1.0f) : 0.0f;

        // rbf: all lanes compute (lanes 32-63 duplicate 0-31), pack, broadcast
        float en = fexp2(NEG_ALPHA_L2 * d);
        float t  = en - meanj;
        float r  = fexp2(NEG_BETA_L2 * t * t) * rc;
        float rdn = __shfl_down(r, 1);
        unsigned ru = packh2(r, rdn);          // lane 2q holds (r_2q, r_2q+1)
        unsigned rbs[16];
        #pragma unroll
        for (int q = 0; q < 16; ++q)
            rbs[q] = (unsigned)__builtin_amdgcn_readlane((int)ru, 2 * q);

        float g1a = ed1, g2a = ed2, g3a = ed3;
        #pragma unroll
        for (int q = 0; q < 16; ++q) {
            h2_t rb = u2h(rbs[q]);
            g1a = FDOT2(u2h(w1u[q]), rb, g1a);
            g2a = FDOT2(u2h(w2u[q]), rb, g2a);
            g3a = FDOT2(u2h(w3u[q]), rb, g3a);
        }

        float zc = zA + t2v;
        float Cc = rc * zc;
        float f1 = g1a * Cc;
        float f2 = g2a * Cc * 10.0f;
        float f3 = g3a * Cc * 100.0f;

        Is += f1;
        sx += f2 * ux;  sy += f2 * uy;  sz += f2 * uz;
        float qq = (ux*ux + uy*uy + uz*uz) * (1.0f / 3.0f);
        Sxx += f3 * (ux*ux - qq);
        Syy += f3 * (uy*uy - qq);
        Szz += f3 * (uz*uz - qq);
        Sxy += f3 * (ux*uy);
        Sxz += f3 * (ux*uz);
        Syz += f3 * (uy*uz);
    }

    // tn + LayerNorm (f32, before any fp16 rounding)
    float tn = 3.0f*Is*Is + 2.0f*(sx*sx + sy*sy + sz*sz)
             + Sxx*Sxx + Syy*Syy + Szz*Szz
             + 2.0f*(Sxy*Sxy + Sxz*Sxz + Syz*Syz);
    float s1 = tn, s2 = tn * tn;
    #pragma unroll
    for (int o = 32; o > 0; o >>= 1) {
        s1 += __shfl_xor(s1, o);
        s2 += __shfl_xor(s2, o);
    }
    float mu  = s1 * (1.0f / 64.0f);
    float var = s2 * (1.0f / 64.0f) - mu * mu;
    float nv  = (tn - mu) * rsqrtf(var + 1e-5f) * (WF + OFF_LNG)[h] + (WF + OFF_LNB)[h];

    // pack 11 vectors (10 accums + nv) to fp16 pairs; even lanes store
    float vals[11] = {Is, sx, sy, sz, Sxx, Syy, Szz, Sxy, Sxz, Syz, nv};
    #pragma unroll
    for (int c = 0; c < 11; ++c) {
        float pv = __shfl_xor(vals[c], 1);
        if ((h & 1) == 0)
            accH[((n * 11 + c) << 5) + (h >> 1)] = packh2(vals[c], pv);
    }
}

// Epilogue: MLP + transform. ls2 fp16 in LDS (stride 68 uints, conflict-free);
// ls1/lt fp16 from global (L1-resident). 2 blocks/CU. (Round-1 known-good.)
__global__ __launch_bounds__(256, 2) void k_post(
    const float* __restrict__ WF,
    const unsigned* __restrict__ PH,
    const unsigned* __restrict__ accH,
    float* __restrict__ out)
{
    __shared__ __align__(16) unsigned wL2[192 * 68];    // 52224 B
    __shared__ __align__(16) unsigned acch[4][12 * 32]; // per-wave: 11 vecs (+pad)
    __shared__ __align__(16) unsigned y1h[4][64];
    __shared__ __align__(16) unsigned y2h[4][96];

    for (int q = threadIdx.x; q < 12288; q += 256) {
        int m = q >> 6, u = q & 63;
        wL2[m * 68 + u] = PH[PH_L2 + q];
    }
    __syncthreads();

    const int wave = threadIdx.x >> 6;
    const int h    = threadIdx.x & 63;
    const int gw   = blockIdx.x * 4 + wave;
    const int GW   = gridDim.x * 4;

    const uint4* l1base = (const uint4*)(PH + PH_L1);
    const uint4* lt0 = (const uint4*)(PH + PH_LT) + h * 8;
    const uint4* lt1 = (const uint4*)(PH + PH_LT + 2048) + h * 8;
    const uint4* lt2 = (const uint4*)(PH + PH_LT + 4096) + h * 8;

    for (int n = gw; n < N_ATOMS; n += GW) {
        // stage this atom's 11 fp16 vectors
        if (h < 32) {
            #pragma unroll
            for (int c = 0; c < 11; ++c)
                acch[wave][c * 32 + h] = accH[((n * 11 + c) << 5) + h];
        }
        __builtin_amdgcn_wave_barrier();

        const uint4* nvh = (const uint4*)&acch[wave][10 * 32];

        // y1 = silu(ls1_w @ nv + b1): j = h, h+64
        float ya = (WF + OFF_L1B)[h];
        float yb = (WF + OFF_L1B)[h + 64];
        {
            const uint4* ra = l1base + h * 8;
            const uint4* rb = l1base + (h + 64) * 8;
            #pragma unroll
            for (int k = 0; k < 8; ++k) {
                ya = dot16h(ra + k, nvh + k, ya);
                yb = dot16h(rb + k, nvh + k, yb);
            }
        }
        ya = fsilu(ya); yb = fsilu(yb);
        {
            float pa = __shfl_xor(ya, 1);
            float pb = __shfl_xor(yb, 1);
            if ((h & 1) == 0) {
                y1h[wave][(h >> 1)]      = packh2(ya, pa);
                y1h[wave][32 + (h >> 1)] = packh2(yb, pb);
            }
        }
        __builtin_amdgcn_wave_barrier();

        // y2 = silu(ls2_w @ y1 + b2): m = h, h+64, h+128
        const uint4* y1p = (const uint4*)&y1h[wave][0];
        float z0 = (WF + OFF_L2B)[h];
        float z1 = (WF + OFF_L2B)[h + 64];
        float z2 = (WF + OFF_L2B)[h + 128];
        {
            const uint4* r0 = (const uint4*)&wL2[(h)       * 68];
            const uint4* r1 = (const uint4*)&wL2[(h + 64)  * 68];
            const uint4* r2 = (const uint4*)&wL2[(h + 128) * 68];
            #pragma unroll
            for (int k = 0; k < 16; ++k) {
                uint4 x = y1p[k];
                uint4 a0 = r0[k], a1 = r1[k], a2 = r2[k];
                z0 = FDOT2(u2h(a0.x), u2h(x.x), z0); z0 = FDOT2(u2h(a0.y), u2h(x.y), z0);
                z0 = FDOT2(u2h(a0.z), u2h(x.z), z0); z0 = FDOT2(u2h(a0.w), u2h(x.w), z0);
                z1 = FDOT2(u2h(a1.x), u2h(x.x), z1); z1 = FDOT2(u2h(a1.y), u2h(x.y), z1);
                z1 = FDOT2(u2h(a1.z), u2h(x.z), z1); z1 = FDOT2(u2h(a1.w), u2h(x.w), z1);
                z2 = FDOT2(u2h(a2.x), u2h(x.x), z2); z2 = FDOT2(u2h(a2.y), u2h(x.y), z2);
                z2 = FDOT2(u2h(a2.z), u2h(x.z), z2); z2 = FDOT2(u2h(a2.w), u2h(x.w), z2);
            }
        }
        z0 = fsilu(z0); z1 = fsilu(z1); z2 = fsilu(z2);
        {
            float p0 = __shfl_xor(z0, 1);
            float p1 = __shfl_xor(z1, 1);
            float p2 = __shfl_xor(z2, 1);
            if ((h & 1) == 0) {
                y2h[wave][(h >> 1)]      = packh2(z0, p0);
                y2h[wave][32 + (h >> 1)] = packh2(z1, p1);
                y2h[wave][64 + (h >> 1)] = packh2(z2, p2);
            }
        }
        __builtin_amdgcn_wave_barrier();

        // norm multipliers n0..n2 = y2[3h..3h+2]
        float n0, n1, n2;
        {
            int i0 = 3 * h;
            unsigned u0 = y2h[wave][i0 >> 1];
            unsigned u1 = y2h[wave][(i0 >> 1) + 1];
            h2_t a = u2h(u0), b = u2h(u1);
            if (i0 & 1) { n0 = (float)a.y; n1 = (float)b.x; n2 = (float)b.y; }
            else        { n0 = (float)a.x; n1 = (float)a.y; n2 = (float)b.x; }
        }

        // transform: 10 dot64 against lt rows
        const uint4* aI  = (const uint4*)&acch[wave][0];
        const uint4* aAx = (const uint4*)&acch[wave][32];
        const uint4* aAy = (const uint4*)&acch[wave][64];
        const uint4* aAz = (const uint4*)&acch[wave][96];
        const uint4* aXX = (const uint4*)&acch[wave][128];
        const uint4* aYY = (const uint4*)&acch[wave][160];
        const uint4* aZZ = (const uint4*)&acch[wave][192];
        const uint4* aXY = (const uint4*)&acch[wave][224];
        const uint4* aXZ = (const uint4*)&acch[wave][256];
        const uint4* aYZ = (const uint4*)&acch[wave][288];

        float P0=0.f, PAx=0.f, PAy=0.f, PAz=0.f;
        float Q0=0.f, Q1=0.f, Q2=0.f, Q3=0.f, Q4=0.f, Q5=0.f;
        #pragma unroll
        for (int k = 0; k < 8; ++k) {
            P0  = dot16h(lt0 + k, aI  + k, P0);
            PAx = dot16h(lt1 + k, aAx + k, PAx);
            PAy = dot16h(lt1 + k, aAy + k, PAy);
            PAz = dot16h(lt1 + k, aAz + k, PAz);
            Q0  = dot16h(lt2 + k, aXX + k, Q0);
            Q1  = dot16h(lt2 + k, aYY + k, Q1);
            Q2  = dot16h(lt2 + k, aZZ + k, Q2);
            Q3  = dot16h(lt2 + k, aXY + k, Q3);
            Q4  = dot16h(lt2 + k, aXZ + k, Q4);
            Q5  = dot16h(lt2 + k, aYZ + k, Q5);
        }
        float Iv = P0 * n0;
        float Ax = PAx * n1, Ay = PAy * n1, Az = PAz * n1;
        float Xx = Q0 * n2, Yy = Q1 * n2, Zz = Q2 * n2;
        float Xy = Q3 * n2, Xz = Q4 * n2, Yz = Q5 * n2;

        float* o = out + (size_t)n * 576 + h * 9;
        o[0] =  Iv + Xx;  o[1] = -Az + Xy;  o[2] =  Ay + Xz;
        o[3] =  Az + Xy;  o[4] =  Iv + Yy;  o[5] = -Ax + Yz;
        o[6] = -Ay + Xz;  o[7] =  Ax + Yz;  o[8] =  Iv + Zz;
        __builtin_amdgcn_wave_barrier();
    }
}

extern "C" void kernel_launch(void* const* d_in, const int* in_sizes, int n_in,
                              void* d_out, int out_size, void* d_ws, size_t ws_size,
                              hipStream_t stream) {
    const int* an   = (const int*)d_in[0];
    const int* pidx = (const int*)d_in[1];

    char* ws = (char*)d_ws;
    float*    WF    = (float*)(ws + WS_WF);
    int*      cnt   = (int*)(ws + WS_CNT);
    int*      offs  = (int*)(ws + WS_OFF);
    int*      cur   = (int*)(ws + WS_CUR);
    float*    T1    = (float*)(ws + WS_T1);
    float*    T2    = (float*)(ws + WS_T2);
    unsigned* PH    = (unsigned*)(ws + WS_PH);
    float4*   dpack = (float4*)(ws + WS_DPK);
    int*      znl   = (int*)(ws + WS_ZNL);
    unsigned* accH  = (unsigned*)(ws + WS_ACCH);
    float*    out   = (float*)d_out;

    hipMemsetAsync(cnt, 0, N_ATOMS * sizeof(int), stream);

    ConvArgs ca;
    for (int i = 0; i < 18; ++i) ca.src[i] = d_in[4 + i];
    ca.dst = WF;
    k_prep<<<491, 256, 0, stream>>>(ca, pidx, cnt, T1, T2, PH);
    k_scan<<<1, 1024, 0, stream>>>(cnt, offs, cur);
    k_fill<<<(N_PAIRS + 255) / 256, 256, 0, stream>>>(pidx, an, d_in[2], d_in[3],
                                                      cur, dpack, znl);
    k_pair<<<2500, 256, 0, stream>>>(an, WF, offs, dpack, znl, T1, T2, PH, accH);
    k_post<<<256, 256, 0, stream>>>(WF, PH, accH, out);
}

// Round 7
// 232.865 us; speedup vs baseline: 1.2375x; 1.0124x over previous
//
#include <hip/hip_runtime.h>
#include <hip/hip_bf16.h>

#define N_ATOMS 10000
#define N_PAIRS 100000
#define HH 64
#define MAXZ 100

// two-level CSR build
#define NB_HIST 64
#define PPB 1563            // ceil(100000/64)

typedef _Float16 h2_t __attribute__((ext_vector_type(2)));

constexpr float RBF_START = 0.6065306597126334f;
constexpr float RBF_STEP  = (1.0f - RBF_START) / 31.0f;
constexpr float RBF_BETA  = 1.0f / ((0.0625f * (1.0f - RBF_START)) * (0.0625f * (1.0f - RBF_START)));
constexpr float LOG2E     = 1.4426950408889634f;
constexpr float NEG_ALPHA_L2 = -10.0f * LOG2E;
constexpr float NEG_BETA_L2  = -RBF_BETA * LOG2E;

// ---- f32 param layout in workspace (element offsets) ----
#define OFF_EMB   0
#define OFF_W2    6400
#define OFF_B2    14592
#define OFF_D1W   14656
#define OFF_D1B   16704
#define OFF_D2W   16768
#define OFF_D2B   18816
#define OFF_D3W   18880
#define OFF_D3B   20928
#define OFF_LT0   20992
#define OFF_LT1   25088
#define OFF_LT2   29184
#define OFF_L1W   33280
#define OFF_L1B   41472
#define OFF_L2W   41600
#define OFF_L2B   66176
#define OFF_LNG   66368
#define OFF_LNB   66432
#define N_PARAMF  66496

// packed-half (uint) region layout inside PH
#define PH_DP   0        // 3 x 64 x 16 uints
#define PH_L1   3072     // 128 x 32
#define PH_L2   7168     // 192 x 64
#define PH_LT   19456    // 3 x 64 x 32
#define PH_N    25600

// ws byte offsets
#define WS_WF     0
#define WS_CNT    266240     // total[] (10000 ints)
#define WS_OFF    307200     // offs[] (10001 ints)
#define WS_T1     389120
#define WS_T2     414720
#define WS_PH     440320
#define WS_DPK    542720
#define WS_ZNL    2142720
#define WS_ACCH   2542720    // accH 14.08 MB; H/SUBraw alias its head (dead before k_pair)
#define WS_H      WS_ACCH                 // 64 x 10000 ints = 2.56 MB
#define WS_SUB    (WS_ACCH + 2560000)     // 64 x 10000 ints = 2.56 MB

__device__ __forceinline__ float bf2f(unsigned short u) {
    return __uint_as_float(((unsigned int)u) << 16);
}
__device__ __forceinline__ float fexp2(float x) { return __builtin_amdgcn_exp2f(x); }
__device__ __forceinline__ float fcos2pi(float x) { return __builtin_amdgcn_cosf(x); }
__device__ __forceinline__ float fsilu(float x) { return x / (1.0f + fexp2(-LOG2E * x)); }
__device__ __forceinline__ h2_t u2h(unsigned u) { return __builtin_bit_cast(h2_t, u); }
__device__ __forceinline__ unsigned packh2(float a, float b) {
    h2_t v; v.x = (_Float16)a; v.y = (_Float16)b;
    return __builtin_bit_cast(unsigned, v);
}

#if __has_builtin(__builtin_amdgcn_fdot2)
__device__ __forceinline__ float FDOT2(h2_t a, h2_t b, float c) {
    return __builtin_amdgcn_fdot2(a, b, c, false);
}
#else
__device__ __forceinline__ float FDOT2(h2_t a, h2_t b, float c) {
    return c + (float)a.x * (float)b.x + (float)a.y * (float)b.y;
}
#endif
__device__ __forceinline__ float dot16h(const uint4* w, const uint4* x, float acc) {
    uint4 a = *w, b = *x;
    acc = FDOT2(u2h(a.x), u2h(b.x), acc);
    acc = FDOT2(u2h(a.y), u2h(b.y), acc);
    acc = FDOT2(u2h(a.z), u2h(b.z), acc);
    acc = FDOT2(u2h(a.w), u2h(b.w), acc);
    return acc;
}

// ---- buffer layout probe: 1 = u16/bf16 array, 0 = f32 ----
__device__ int classify64(const unsigned short* b, int lane) {
    unsigned short x = b[lane];
    int e = (x >> 7) & 0xFF;
    bool implaus = (x != 0) && (e < 96 || e > 133);
    bool zeroeven = ((lane & 1) == 0) && (x == 0);
    unsigned long long mi = __ballot(implaus);
    unsigned long long mz = __ballot(zeroeven);
    if (__popcll(mz) == 32) return 0;
    if (__popcll(mi) >= 8) return 0;
    return 1;
}

__device__ __forceinline__ float ldp(const void* p, int off, int fl) {
    if (fl == 1) return bf2f(((const unsigned short*)p)[off]);
    return ((const float*)p)[off];
}

struct ConvArgs { const void* src[18]; float* dst; };

// Fused: conv (blocks 0..259) | tabpack (260..359) | LDS-histogram (360..423).
// NO global atomics anywhere (round-6 counters: 100K device-scope atomicAdds
// in the old counting pass = 5.1MB write-through + 53us drain, VALUBusy 0.006%).
__global__ void k_prep(ConvArgs a, const int* __restrict__ pidx,
                       float* __restrict__ T1, float* __restrict__ T2,
                       unsigned* __restrict__ PH, int* __restrict__ H) {
    const int sizes[18] = {6400,8192,64,2048,64,2048,64,2048,64,4096,4096,4096,8192,128,24576,192,64,64};
    __shared__ int lh[N_ATOMS];     // used by hist blocks only (40 KB)
    __shared__ int fl;
    if (threadIdx.x < 64) {
        int f = classify64((const unsigned short*)a.src[0], threadIdx.x);
        if (threadIdx.x == 0) fl = f;
    }
    __syncthreads();

    if (blockIdx.x < 260) {
        int t = blockIdx.x * 256 + threadIdx.x;
        if (t < N_PARAMF) {
            int acc = 0, seg = 0, off = t;
            #pragma unroll
            for (int i = 0; i < 18; ++i) {
                if (t >= acc && t < acc + sizes[i]) { seg = i; off = t - acc; }
                acc += sizes[i];
            }
            a.dst[t] = ldp(a.src[seg], off, fl);
        }
        return;
    }

    if (blockIdx.x < 360) {
        // ---- tabpack blocks ----
        int zb = blockIdx.x - 260;            // 0..99
        int h = threadIdx.x;
        if (h < 64) {
            float s1 = 0.f, s2 = 0.f;
            #pragma unroll
            for (int k = 0; k < 64; ++k) {
                float e = ldp(a.src[0], zb * HH + k, fl);          // emb[z][k]
                s1 += ldp(a.src[1], h * 128 + k, fl) * e;          // emb2_w rows
                s2 += ldp(a.src[1], h * 128 + 64 + k, fl) * e;
            }
            T1[zb * HH + h] = s1;
            T2[zb * HH + h] = s2;
        }
        int q = zb * 256 + threadIdx.x;       // 0..25599
        const void* sp; int off;
        if (q < PH_L1) {
            int w = q >> 10, r = q & 1023;
            sp = a.src[3 + 2 * w];            // dp1_w / dp2_w / dp3_w
            off = r * 2;
        } else if (q < PH_L2) {
            sp = a.src[12]; off = (q - PH_L1) * 2;                 // ls1_w
        } else if (q < PH_LT) {
            sp = a.src[14]; off = (q - PH_L2) * 2;                 // ls2_w
        } else {
            int tt = q - PH_LT;
            sp = a.src[9 + (tt >> 11)]; off = (tt & 2047) * 2;     // lt0/lt1/lt2
        }
        PH[q] = packh2(ldp(sp, off, fl), ldp(sp, off + 1, fl));
        return;
    }

    // ---- histogram blocks: LDS atomics only ----
    int b = blockIdx.x - 360;                 // 0..63
    for (int i = threadIdx.x; i < N_ATOMS; i += 256) lh[i] = 0;
    __syncthreads();
    int p0 = b * PPB;
    int p1 = p0 + PPB; if (p1 > N_PAIRS) p1 = N_PAIRS;
    for (int p = p0 + threadIdx.x; p < p1; p += 256)
        atomicAdd(&lh[pidx[p]], 1);           // LDS atomic (per-CU, cheap)
    __syncthreads();
    for (int i = threadIdx.x; i < N_ATOMS; i += 256)
        H[b * N_ATOMS + i] = lh[i];
}

// Per-atom reduction over hist blocks: total[s] and exclusive per-block
// prefix SUBraw[b][s]. Coalesced in s for both reads and writes.
__global__ void k_red(const int* __restrict__ H, int* __restrict__ SUBr,
                      int* __restrict__ total) {
    int s = blockIdx.x * 256 + threadIdx.x;
    if (s >= N_ATOMS) return;
    int run = 0;
    #pragma unroll 8
    for (int b = 0; b < NB_HIST; ++b) {
        SUBr[b * N_ATOMS + s] = run;
        run += H[b * N_ATOMS + s];
    }
    total[s] = run;
}

// shfl-based scan over total[] -> offs[].
__global__ void k_scan(const int* __restrict__ total, int* __restrict__ offs) {
    __shared__ int wsum[16];
    int tid = threadIdx.x;                // 0..1023
    int lane = tid & 63, wid = tid >> 6;
    int base = tid * 10;
    int c[10]; int s = 0;
    #pragma unroll
    for (int i = 0; i < 10; ++i) {
        int idx = base + i;
        int v = (idx < N_ATOMS) ? total[idx] : 0;
        c[i] = v; s += v;
    }
    int inc = s;
    #pragma unroll
    for (int o = 1; o < 64; o <<= 1) {
        int v = __shfl_up(inc, o);
        if (lane >= o) inc += v;
    }
    if (lane == 63) wsum[wid] = inc;
    __syncthreads();
    int wbase = 0;
    #pragma unroll
    for (int w = 0; w < 16; ++w) {
        int v = wsum[w];
        if (w < wid) wbase += v;
    }
    int run = wbase + (inc - s);          // exclusive prefix for this thread
    #pragma unroll
    for (int i = 0; i < 10; ++i) {
        int idx = base + i;
        if (idx < N_ATOMS) { offs[idx] = run; run += c[i]; }
    }
    if (tid == 0) offs[N_ATOMS] = N_PAIRS;
}

// Scatter fill: pos = offs[s] + SUBraw[b][s] + local_rank (LDS atomic).
// Bijective slot assignment, zero global atomics.
__global__ void k_fill(const int* __restrict__ pidx, const int* __restrict__ an,
                       const void* __restrict__ dij_v, const void* __restrict__ rij_v,
                       const int* __restrict__ offs, const int* __restrict__ SUBr,
                       float4* __restrict__ dpack, int* __restrict__ znl) {
    __shared__ int lh[N_ATOMS];
    __shared__ int fdr[2];
    if (threadIdx.x < 64) {
        int fd = classify64((const unsigned short*)dij_v, threadIdx.x);
        int fr = classify64((const unsigned short*)rij_v, threadIdx.x);
        if (threadIdx.x == 0) { fdr[0] = fd; fdr[1] = fr; }
    }
    for (int i = threadIdx.x; i < N_ATOMS; i += 256) lh[i] = 0;
    __syncthreads();
    int b = blockIdx.x;
    int p0 = b * PPB;
    int p1 = p0 + PPB; if (p1 > N_PAIRS) p1 = N_PAIRS;
    for (int p = p0 + threadIdx.x; p < p1; p += 256) {
        int s = pidx[p];
        int dst = pidx[N_PAIRS + p];
        int lr = atomicAdd(&lh[s], 1);    // LDS atomic
        int pos = offs[s] + SUBr[b * N_ATOMS + s] + lr;
        float d, rx, ry, rz;
        if (fdr[0] == 1) d = bf2f(((const unsigned short*)dij_v)[p]);
        else             d = ((const float*)dij_v)[p];
        if (fdr[1] == 1) {
            const unsigned short* r = (const unsigned short*)rij_v;
            rx = bf2f(r[3*p]); ry = bf2f(r[3*p+1]); rz = bf2f(r[3*p+2]);
        } else {
            const float* r = (const float*)rij_v;
            rx = r[3*p]; ry = r[3*p+1]; rz = r[3*p+2];
        }
        dpack[pos] = make_float4(rx, ry, rz, d);
        znl[pos] = an[dst];
    }
}

// Pair accumulation (round-6 known-good: zero LDS, readlane rbf broadcast,
// pinned weight hoist). 4 waves/block, 1 atom/wave, 2500 blocks.
__global__ __launch_bounds__(256, 2) void k_pair(
    const int* __restrict__ an,
    const float* __restrict__ WF,
    const int* __restrict__ offs,
    const float4* __restrict__ dpack, const int* __restrict__ znl,
    const float* __restrict__ T1, const float* __restrict__ T2,
    const unsigned* __restrict__ PH,
    unsigned* __restrict__ accH)
{
    const int wave = threadIdx.x >> 6;
    const int h    = threadIdx.x & 63;
    const int n    = blockIdx.x * 4 + wave;

    // hoist per-lane dp weight rows (48 scalars) into registers, pinned
    unsigned w1u[16], w2u[16], w3u[16];
    {
        const uint4* g1 = (const uint4*)(PH + PH_DP + 0 * 1024 + h * 16);
        const uint4* g2 = (const uint4*)(PH + PH_DP + 1 * 1024 + h * 16);
        const uint4* g3 = (const uint4*)(PH + PH_DP + 2 * 1024 + h * 16);
        #pragma unroll
        for (int k = 0; k < 4; ++k) {
            uint4 a = g1[k]; w1u[4*k] = a.x; w1u[4*k+1] = a.y; w1u[4*k+2] = a.z; w1u[4*k+3] = a.w;
            uint4 b = g2[k]; w2u[4*k] = b.x; w2u[4*k+1] = b.y; w2u[4*k+2] = b.z; w2u[4*k+3] = b.w;
            uint4 c = g3[k]; w3u[4*k] = c.x; w3u[4*k+1] = c.y; w3u[4*k+2] = c.z; w3u[4*k+3] = c.w;
        }
    }
    #pragma unroll
    for (int q = 0; q < 16; ++q)
        asm volatile("" : "+v"(w1u[q]), "+v"(w2u[q]), "+v"(w3u[q]));

    const float ed1 = (WF + OFF_D1B)[h];
    const float ed2 = (WF + OFF_D2B)[h];
    const float ed3 = (WF + OFF_D3B)[h];
    const float zA  = (WF + OFF_B2)[h] + T1[an[n] * HH + h];

    float Is=0.f, sx=0.f, sy=0.f, sz=0.f;
    float Sxx=0.f, Syy=0.f, Szz=0.f, Sxy=0.f, Sxz=0.f, Syz=0.f;

    const int pbeg = offs[n], pend = offs[n + 1];

    const float meanj = RBF_START + RBF_STEP * (float)(h & 31);

    // software pipeline: dpack 2-ahead, T2 1-ahead, znl 2-ahead
    float4 dp_cur = make_float4(0.f, 0.f, 0.f, 1.f);
    float4 dp_nxt = make_float4(0.f, 0.f, 0.f, 1.f);
    float  t2cur  = 0.f;
    int    zn_n   = 0;
    if (pbeg < pend) {
        dp_cur = dpack[pbeg];
        t2cur  = T2[znl[pbeg] * HH + h];
        if (pbeg + 1 < pend) {
            dp_nxt = dpack[pbeg + 1];
            zn_n   = znl[pbeg + 1];
        }
    }

    for (int ii = pbeg; ii < pend; ++ii) {
        const float4 dpv = dp_cur;
        const float  t2v = t2cur;
        dp_cur = dp_nxt;
        if (ii + 2 < pend) dp_nxt = dpack[ii + 2];
        if (ii + 1 < pend) t2cur  = T2[zn_n * HH + h];
        if (ii + 2 < pend) zn_n   = znl[ii + 2];

        float d = dpv.w;
        float inv = 1.0f / d;
        float ux = dpv.x*inv, uy = dpv.y*inv, uz = dpv.z*inv;
        float rc = (d < 0.5f) ? 0.5f * (fcos2pi(d) + 1.0f) : 0.0f;

        // rbf: all lanes compute (lanes 32-63 duplicate 0-31), pack, broadcast
        float en = fexp2(NEG_ALPHA_L2 * d);
        float t  = en - meanj;
        float r  = fexp2(NEG_BETA_L2 * t * t) * rc;
        float rdn = __shfl_down(r, 1);
        unsigned ru = packh2(r, rdn);          // lane 2q holds (r_2q, r_2q+1)
        unsigned rbs[16];
        #pragma unroll
        for (int q = 0; q < 16; ++q)
            rbs[q] = (unsigned)__builtin_amdgcn_readlane((int)ru, 2 * q);

        float g1a = ed1, g2a = ed2, g3a = ed3;
        #pragma unroll
        for (int q = 0; q < 16; ++q) {
            h2_t rb = u2h(rbs[q]);
            g1a = FDOT2(u2h(w1u[q]), rb, g1a);
            g2a = FDOT2(u2h(w2u[q]), rb, g2a);
            g3a = FDOT2(u2h(w3u[q]), rb, g3a);
        }

        float zc = zA + t2v;
        float Cc = rc * zc;
        float f1 = g1a * Cc;
        float f2 = g2a * Cc * 10.0f;
        float f3 = g3a * Cc * 100.0f;

        Is += f1;
        sx += f2 * ux;  sy += f2 * uy;  sz += f2 * uz;
        float qq = (ux*ux + uy*uy + uz*uz) * (1.0f / 3.0f);
        Sxx += f3 * (ux*ux - qq);
        Syy += f3 * (uy*uy - qq);
        Szz += f3 * (uz*uz - qq);
        Sxy += f3 * (ux*uy);
        Sxz += f3 * (ux*uz);
        Syz += f3 * (uy*uz);
    }

    // tn + LayerNorm (f32, before any fp16 rounding)
    float tn = 3.0f*Is*Is + 2.0f*(sx*sx + sy*sy + sz*sz)
             + Sxx*Sxx + Syy*Syy + Szz*Szz
             + 2.0f*(Sxy*Sxy + Sxz*Sxz + Syz*Syz);
    float s1 = tn, s2 = tn * tn;
    #pragma unroll
    for (int o = 32; o > 0; o >>= 1) {
        s1 += __shfl_xor(s1, o);
        s2 += __shfl_xor(s2, o);
    }
    float mu  = s1 * (1.0f / 64.0f);
    float var = s2 * (1.0f / 64.0f) - mu * mu;
    float nv  = (tn - mu) * rsqrtf(var + 1e-5f) * (WF + OFF_LNG)[h] + (WF + OFF_LNB)[h];

    // pack 11 vectors (10 accums + nv) to fp16 pairs; even lanes store
    float vals[11] = {Is, sx, sy, sz, Sxx, Syy, Szz, Sxy, Sxz, Syz, nv};
    #pragma unroll
    for (int c = 0; c < 11; ++c) {
        float pv = __shfl_xor(vals[c], 1);
        if ((h & 1) == 0)
            accH[((n * 11 + c) << 5) + (h >> 1)] = packh2(vals[c], pv);
    }
}

// Epilogue: MLP + transform. ls2 fp16 in LDS (stride 68 uints, conflict-free);
// ls1/lt fp16 from global (L1-resident). 2 blocks/CU. (Round-1/6 known-good.)
__global__ __launch_bounds__(256, 2) void k_post(
    const float* __restrict__ WF,
    const unsigned* __restrict__ PH,
    const unsigned* __restrict__ accH,
    float* __restrict__ out)
{
    __shared__ __align__(16) unsigned wL2[192 * 68];    // 52224 B
    __shared__ __align__(16) unsigned acch[4][12 * 32]; // per-wave: 11 vecs (+pad)
    __shared__ __align__(16) unsigned y1h[4][64];
    __shared__ __align__(16) unsigned y2h[4][96];

    for (int q = threadIdx.x; q < 12288; q += 256) {
        int m = q >> 6, u = q & 63;
        wL2[m * 68 + u] = PH[PH_L2 + q];
    }
    __syncthreads();

    const int wave = threadIdx.x >> 6;
    const int h    = threadIdx.x & 63;
    const int gw   = blockIdx.x * 4 + wave;
    const int GW   = gridDim.x * 4;

    const uint4* l1base = (const uint4*)(PH + PH_L1);
    const uint4* lt0 = (const uint4*)(PH + PH_LT) + h * 8;
    const uint4* lt1 = (const uint4*)(PH + PH_LT + 2048) + h * 8;
    const uint4* lt2 = (const uint4*)(PH + PH_LT + 4096) + h * 8;

    for (int n = gw; n < N_ATOMS; n += GW) {
        // stage this atom's 11 fp16 vectors
        if (h < 32) {
            #pragma unroll
            for (int c = 0; c < 11; ++c)
                acch[wave][c * 32 + h] = accH[((n * 11 + c) << 5) + h];
        }
        __builtin_amdgcn_wave_barrier();

        const uint4* nvh = (const uint4*)&acch[wave][10 * 32];

        // y1 = silu(ls1_w @ nv + b1): j = h, h+64
        float ya = (WF + OFF_L1B)[h];
        float yb = (WF + OFF_L1B)[h + 64];
        {
            const uint4* ra = l1base + h * 8;
            const uint4* rb = l1base + (h + 64) * 8;
            #pragma unroll
            for (int k = 0; k < 8; ++k) {
                ya = dot16h(ra + k, nvh + k, ya);
                yb = dot16h(rb + k, nvh + k, yb);
            }
        }
        ya = fsilu(ya); yb = fsilu(yb);
        {
            float pa = __shfl_xor(ya, 1);
            float pb = __shfl_xor(yb, 1);
            if ((h & 1) == 0) {
                y1h[wave][(h >> 1)]      = packh2(ya, pa);
                y1h[wave][32 + (h >> 1)] = packh2(yb, pb);
            }
        }
        __builtin_amdgcn_wave_barrier();

        // y2 = silu(ls2_w @ y1 + b2): m = h, h+64, h+128
        const uint4* y1p = (const uint4*)&y1h[wave][0];
        float z0 = (WF + OFF_L2B)[h];
        float z1 = (WF + OFF_L2B)[h + 64];
        float z2 = (WF + OFF_L2B)[h + 128];
        {
            const uint4* r0 = (const uint4*)&wL2[(h)       * 68];
            const uint4* r1 = (const uint4*)&wL2[(h + 64)  * 68];
            const uint4* r2 = (const uint4*)&wL2[(h + 128) * 68];
            #pragma unroll
            for (int k = 0; k < 16; ++k) {
                uint4 x = y1p[k];
                uint4 a0 = r0[k], a1 = r1[k], a2 = r2[k];
                z0 = FDOT2(u2h(a0.x), u2h(x.x), z0); z0 = FDOT2(u2h(a0.y), u2h(x.y), z0);
                z0 = FDOT2(u2h(a0.z), u2h(x.z), z0); z0 = FDOT2(u2h(a0.w), u2h(x.w), z0);
                z1 = FDOT2(u2h(a1.x), u2h(x.x), z1); z1 = FDOT2(u2h(a1.y), u2h(x.y), z1);
                z1 = FDOT2(u2h(a1.z), u2h(x.z), z1); z1 = FDOT2(u2h(a1.w), u2h(x.w), z1);
                z2 = FDOT2(u2h(a2.x), u2h(x.x), z2); z2 = FDOT2(u2h(a2.y), u2h(x.y), z2);
                z2 = FDOT2(u2h(a2.z), u2h(x.z), z2); z2 = FDOT2(u2h(a2.w), u2h(x.w), z2);
            }
        }
        z0 = fsilu(z0); z1 = fsilu(z1); z2 = fsilu(z2);
        {
            float p0 = __shfl_xor(z0, 1);
            float p1 = __shfl_xor(z1, 1);
            float p2 = __shfl_xor(z2, 1);
            if ((h & 1) == 0) {
                y2h[wave][(h >> 1)]      = packh2(z0, p0);
                y2h[wave][32 + (h >> 1)] = packh2(z1, p1);
                y2h[wave][64 + (h >> 1)] = packh2(z2, p2);
            }
        }
        __builtin_amdgcn_wave_barrier();

        // norm multipliers n0..n2 = y2[3h..3h+2]
        float n0, n1, n2;
        {
            int i0 = 3 * h;
            unsigned u0 = y2h[wave][i0 >> 1];
            unsigned u1 = y2h[wave][(i0 >> 1) + 1];
            h2_t a = u2h(u0), b = u2h(u1);
            if (i0 & 1) { n0 = (float)a.y; n1 = (float)b.x; n2 = (float)b.y; }
            else        { n0 = (float)a.x; n1 = (float)a.y; n2 = (float)b.x; }
        }

        // transform: 10 dot64 against lt rows
        const uint4* aI  = (const uint4*)&acch[wave][0];
        const uint4* aAx = (const uint4*)&acch[wave][32];
        const uint4* aAy = (const uint4*)&acch[wave][64];
        const uint4* aAz = (const uint4*)&acch[wave][96];
        const uint4* aXX = (const uint4*)&acch[wave][128];
        const uint4* aYY = (const uint4*)&acch[wave][160];
        const uint4* aZZ = (const uint4*)&acch[wave][192];
        const uint4* aXY = (const uint4*)&acch[wave][224];
        const uint4* aXZ = (const uint4*)&acch[wave][256];
        const uint4* aYZ = (const uint4*)&acch[wave][288];

        float P0=0.f, PAx=0.f, PAy=0.f, PAz=0.f;
        float Q0=0.f, Q1=0.f, Q2=0.f, Q3=0.f, Q4=0.f, Q5=0.f;
        #pragma unroll
        for (int k = 0; k < 8; ++k) {
            P0  = dot16h(lt0 + k, aI  + k, P0);
            PAx = dot16h(lt1 + k, aAx + k, PAx);
            PAy = dot16h(lt1 + k, aAy + k, PAy);
            PAz = dot16h(lt1 + k, aAz + k, PAz);
            Q0  = dot16h(lt2 + k, aXX + k, Q0);
            Q1  = dot16h(lt2 + k, aYY + k, Q1);
            Q2  = dot16h(lt2 + k, aZZ + k, Q2);
            Q3  = dot16h(lt2 + k, aXY + k, Q3);
            Q4  = dot16h(lt2 + k, aXZ + k, Q4);
            Q5  = dot16h(lt2 + k, aYZ + k, Q5);
        }
        float Iv = P0 * n0;
        float Ax = PAx * n1, Ay = PAy * n1, Az = PAz * n1;
        float Xx = Q0 * n2, Yy = Q1 * n2, Zz = Q2 * n2;
        float Xy = Q3 * n2, Xz = Q4 * n2, Yz = Q5 * n2;

        float* o = out + (size_t)n * 576 + h * 9;
        o[0] =  Iv + Xx;  o[1] = -Az + Xy;  o[2] =  Ay + Xz;
        o[3] =  Az + Xy;  o[4] =  Iv + Yy;  o[5] = -Ax + Yz;
        o[6] = -Ay + Xz;  o[7] =  Ax + Yz;  o[8] =  Iv + Zz;
        __builtin_amdgcn_wave_barrier();
    }
}

extern "C" void kernel_launch(void* const* d_in, const int* in_sizes, int n_in,
                              void* d_out, int out_size, void* d_ws, size_t ws_size,
                              hipStream_t stream) {
    const int* an   = (const int*)d_in[0];
    const int* pidx = (const int*)d_in[1];

    char* ws = (char*)d_ws;
    float*    WF    = (float*)(ws + WS_WF);
    int*      total = (int*)(ws + WS_CNT);
    int*      offs  = (int*)(ws + WS_OFF);
    float*    T1    = (float*)(ws + WS_T1);
    float*    T2    = (float*)(ws + WS_T2);
    unsigned* PH    = (unsigned*)(ws + WS_PH);
    float4*   dpack = (float4*)(ws + WS_DPK);
    int*      znl   = (int*)(ws + WS_ZNL);
    int*      H     = (int*)(ws + WS_H);
    int*      SUBr  = (int*)(ws + WS_SUB);
    unsigned* accH  = (unsigned*)(ws + WS_ACCH);
    float*    out   = (float*)d_out;

    ConvArgs ca;
    for (int i = 0; i < 18; ++i) ca.src[i] = d_in[4 + i];
    ca.dst = WF;
    k_prep<<<424, 256, 0, stream>>>(ca, pidx, T1, T2, PH, H);
    k_red<<<40, 256, 0, stream>>>(H, SUBr, total);
    k_scan<<<1, 1024, 0, stream>>>(total, offs);
    k_fill<<<NB_HIST, 256, 0, stream>>>(pidx, an, d_in[2], d_in[3],
                                        offs, SUBr, dpack, znl);
    k_pair<<<2500, 256, 0, stream>>>(an, WF, offs, dpack, znl, T1, T2, PH, accH);
    k_post<<<256, 256, 0, stream>>>(WF, PH, accH, out);
}

// Round 9
// 200.521 us; speedup vs baseline: 1.4371x; 1.1613x over previous
//
#include <hip/hip_runtime.h>
#include <hip/hip_bf16.h>

#define N_ATOMS 10000
#define N_PAIRS 100000
#define HH 64
#define MAXZ 100

typedef _Float16 h2_t __attribute__((ext_vector_type(2)));

constexpr float RBF_START = 0.6065306597126334f;
constexpr float RBF_STEP  = (1.0f - RBF_START) / 31.0f;
constexpr float RBF_BETA  = 1.0f / ((0.0625f * (1.0f - RBF_START)) * (0.0625f * (1.0f - RBF_START)));
constexpr float LOG2E     = 1.4426950408889634f;
constexpr float NEG_ALPHA_L2 = -10.0f * LOG2E;
constexpr float NEG_BETA_L2  = -RBF_BETA * LOG2E;

// ---- f32 param layout in workspace (element offsets) ----
#define OFF_EMB   0
#define OFF_W2    6400
#define OFF_B2    14592
#define OFF_D1W   14656
#define OFF_D1B   16704
#define OFF_D2W   16768
#define OFF_D2B   18816
#define OFF_D3W   18880
#define OFF_D3B   20928
#define OFF_LT0   20992
#define OFF_LT1   25088
#define OFF_LT2   29184
#define OFF_L1W   33280
#define OFF_L1B   41472
#define OFF_L2W   41600
#define OFF_L2B   66176
#define OFF_LNG   66368
#define OFF_LNB   66432
#define N_PARAMF  66496

// packed-half (uint) region layout inside PH
#define PH_DP   0        // 3 x 64 x 16 uints
#define PH_L1   3072     // 128 x 32
#define PH_L2   7168     // 192 x 64
#define PH_LT   19456    // 3 x 64 x 32
#define PH_N    25600

// ws byte offsets
#define WS_WF     0
#define WS_CNT    266240
#define WS_OFF    307200
#define WS_CUR    348160
#define WS_T1     389120
#define WS_T2     414720
#define WS_PH     440320
#define WS_DPK    542720
#define WS_ZNL    2142720
#define WS_ACCH   2542720   // 10000 x 11 x 32 uints = 14.08 MB

__device__ __forceinline__ float bf2f(unsigned short u) {
    return __uint_as_float(((unsigned int)u) << 16);
}
__device__ __forceinline__ float fexp2(float x) { return __builtin_amdgcn_exp2f(x); }
__device__ __forceinline__ float fcos2pi(float x) { return __builtin_amdgcn_cosf(x); }
__device__ __forceinline__ float fsilu(float x) { return x / (1.0f + fexp2(-LOG2E * x)); }
__device__ __forceinline__ h2_t u2h(unsigned u) { return __builtin_bit_cast(h2_t, u); }
__device__ __forceinline__ unsigned packh2(float a, float b) {
    h2_t v; v.x = (_Float16)a; v.y = (_Float16)b;
    return __builtin_bit_cast(unsigned, v);
}

#if __has_builtin(__builtin_amdgcn_fdot2)
__device__ __forceinline__ float FDOT2(h2_t a, h2_t b, float c) {
    return __builtin_amdgcn_fdot2(a, b, c, false);
}
#else
__device__ __forceinline__ float FDOT2(h2_t a, h2_t b, float c) {
    return c + (float)a.x * (float)b.x + (float)a.y * (float)b.y;
}
#endif
__device__ __forceinline__ float dot16h(const uint4* w, const uint4* x, float acc) {
    // 16 halves: one uint4 of weights vs one uint4 of rhs
    uint4 a = *w, b = *x;
    acc = FDOT2(u2h(a.x), u2h(b.x), acc);
    acc = FDOT2(u2h(a.y), u2h(b.y), acc);
    acc = FDOT2(u2h(a.z), u2h(b.z), acc);
    acc = FDOT2(u2h(a.w), u2h(b.w), acc);
    return acc;
}
__device__ __forceinline__ float dot16v(uint4 a, uint4 b, float acc) {
    acc = FDOT2(u2h(a.x), u2h(b.x), acc);
    acc = FDOT2(u2h(a.y), u2h(b.y), acc);
    acc = FDOT2(u2h(a.z), u2h(b.z), acc);
    acc = FDOT2(u2h(a.w), u2h(b.w), acc);
    return acc;
}

// ---- buffer layout probe: 1 = u16/bf16 array, 0 = f32 ----
__device__ int classify64(const unsigned short* b, int lane) {
    unsigned short x = b[lane];
    int e = (x >> 7) & 0xFF;
    bool implaus = (x != 0) && (e < 96 || e > 133);
    bool zeroeven = ((lane & 1) == 0) && (x == 0);
    unsigned long long mi = __ballot(implaus);
    unsigned long long mz = __ballot(zeroeven);
    if (__popcll(mz) == 32) return 0;
    if (__popcll(mi) >= 8) return 0;
    return 1;
}

struct ConvArgs { const void* src[18]; float* dst; };

// conv (params -> f32 WF) + pair counting, fused. cnt pre-zeroed by memset.
// (R1-exact: the 207.1us-measured configuration.)
__global__ void k_prep(ConvArgs a, const int* __restrict__ pidx, int* __restrict__ cnt) {
    const int sizes[18] = {6400,8192,64,2048,64,2048,64,2048,64,4096,4096,4096,8192,128,24576,192,64,64};
    __shared__ int fl;
    if (threadIdx.x < 64) {
        int f = classify64((const unsigned short*)a.src[0], threadIdx.x);
        if (threadIdx.x == 0) fl = f;
    }
    __syncthreads();
    int t = blockIdx.x * 256 + threadIdx.x;
    if (t < N_PARAMF) {
        int acc = 0, seg = 0, off = t;
        #pragma unroll
        for (int i = 0; i < 18; ++i) {
            if (t >= acc && t < acc + sizes[i]) { seg = i; off = t - acc; }
            acc += sizes[i];
        }
        if (fl == 1) a.dst[t] = bf2f(((const unsigned short*)a.src[seg])[off]);
        else         a.dst[t] = ((const float*)a.src[seg])[off];
    }
    if (t < N_PAIRS) atomicAdd(&cnt[pidx[t]], 1);
}

// T1/T2 tables + fp16 weight packing. grid 100 x 256 (one uint per thread).
__global__ void k_tabpack(const float* __restrict__ WF, float* __restrict__ T1,
                          float* __restrict__ T2, unsigned* __restrict__ PH) {
    int z = blockIdx.x;
    int h = threadIdx.x;
    if (h < 64) {
        const float* ez = WF + OFF_EMB + z * HH;
        const float* w2 = WF + OFF_W2 + h * 128;
        float s1 = 0.f, s2 = 0.f;
        #pragma unroll
        for (int k = 0; k < 64; ++k) {
            float e = ez[k];
            s1 += w2[k] * e;
            s2 += w2[64 + k] * e;
        }
        T1[z * HH + h] = s1;
        T2[z * HH + h] = s2;
    }
    int q = blockIdx.x * 256 + threadIdx.x;   // 0..25599
    int src;
    if (q < PH_L1) {
        int w = q >> 10, r = q & 1023;
        src = (w == 0 ? OFF_D1W : (w == 1 ? OFF_D2W : OFF_D3W)) + r * 2;
    } else if (q < PH_L2) {
        src = OFF_L1W + (q - PH_L1) * 2;
    } else if (q < PH_LT) {
        src = OFF_L2W + (q - PH_L2) * 2;
    } else {
        src = OFF_LT0 + (q - PH_LT) * 2;      // lt0/lt1/lt2 contiguous
    }
    PH[q] = packh2(WF[src], WF[src + 1]);
}

__global__ void k_scan(const int* __restrict__ cnt, int* __restrict__ offs, int* __restrict__ cur) {
    __shared__ int buf[1024];
    int tid = threadIdx.x;
    int base = tid * 10;
    int c[10]; int s = 0;
    #pragma unroll
    for (int i = 0; i < 10; ++i) {
        int idx = base + i;
        int v = (idx < N_ATOMS) ? cnt[idx] : 0;
        c[i] = v; s += v;
    }
    buf[tid] = s;
    __syncthreads();
    for (int off = 1; off < 1024; off <<= 1) {
        int v = (tid >= off) ? buf[tid - off] : 0;
        __syncthreads();
        buf[tid] += v;
        __syncthreads();
    }
    int run = buf[tid] - s;
    #pragma unroll
    for (int i = 0; i < 10; ++i) {
        int idx = base + i;
        if (idx < N_ATOMS) { offs[idx] = run; cur[idx] = run; run += c[i]; }
    }
    if (tid == 0) offs[N_ATOMS] = N_PAIRS;
}

__global__ void k_fill(const int* __restrict__ pidx, const int* __restrict__ an,
                       const void* __restrict__ dij_v, const void* __restrict__ rij_v,
                       int* __restrict__ cur,
                       float4* __restrict__ dpack, int* __restrict__ znl) {
    __shared__ int fdr[2];
    if (threadIdx.x < 64) {
        int fd = classify64((const unsigned short*)dij_v, threadIdx.x);
        int fr = classify64((const unsigned short*)rij_v, threadIdx.x);
        if (threadIdx.x == 0) { fdr[0] = fd; fdr[1] = fr; }
    }
    __syncthreads();
    int p = blockIdx.x * 256 + threadIdx.x;
    if (p >= N_PAIRS) return;
    int s = pidx[p];
    int dst = pidx[N_PAIRS + p];
    int pos = atomicAdd(&cur[s], 1);
    float d, rx, ry, rz;
    if (fdr[0] == 1) d = bf2f(((const unsigned short*)dij_v)[p]);
    else             d = ((const float*)dij_v)[p];
    if (fdr[1] == 1) {
        const unsigned short* r = (const unsigned short*)rij_v;
        rx = bf2f(r[3*p]); ry = bf2f(r[3*p+1]); rz = bf2f(r[3*p+2]);
    } else {
        const float* r = (const float*)rij_v;
        rx = r[3*p]; ry = r[3*p+1]; rz = r[3*p+2];
    }
    dpack[pos] = make_float4(rx, ry, rz, d);
    znl[pos] = an[dst];
}

// Pair accumulation: 4 waves/block, 1 atom/wave, dp weights hoisted to VGPRs.
// (R1-exact: this configuration measured 207.1us total; all later k_pair
// variants — (256,2)/(256,5) bounds, keepalive, readlane broadcast, fusion —
// measured worse at pipeline level. Do not touch without an A/B.)
__global__ __launch_bounds__(256, 4) void k_pair(
    const int* __restrict__ an,
    const float* __restrict__ WF,
    const int* __restrict__ offs,
    const float4* __restrict__ dpack, const int* __restrict__ znl,
    const float* __restrict__ T1, const float* __restrict__ T2,
    const unsigned* __restrict__ PH,
    unsigned* __restrict__ accH)
{
    __shared__ __align__(16) unsigned rbq[4 * 16];

    const int wave = threadIdx.x >> 6;
    const int h    = threadIdx.x & 63;
    const int n    = blockIdx.x * 4 + wave;

    _Float16* rbfh = (_Float16*)&rbq[wave * 16];
    const uint4* rbp = (const uint4*)&rbq[wave * 16];

    // hoist per-lane dp weight rows (16 uints = 32 halves each) into registers
    const uint4* g1 = (const uint4*)(PH + PH_DP + 0 * 1024 + h * 16);
    const uint4* g2 = (const uint4*)(PH + PH_DP + 1 * 1024 + h * 16);
    const uint4* g3 = (const uint4*)(PH + PH_DP + 2 * 1024 + h * 16);
    uint4 w1r[4], w2r[4], w3r[4];
    #pragma unroll
    for (int k = 0; k < 4; ++k) {
        w1r[k] = g1[k];
        w2r[k] = g2[k];
        w3r[k] = g3[k];
    }

    const float ed1 = (WF + OFF_D1B)[h];
    const float ed2 = (WF + OFF_D2B)[h];
    const float ed3 = (WF + OFF_D3B)[h];
    const float zA  = (WF + OFF_B2)[h] + T1[an[n] * HH + h];

    float Is=0.f, sx=0.f, sy=0.f, sz=0.f;
    float Sxx=0.f, Syy=0.f, Szz=0.f, Sxy=0.f, Sxz=0.f, Syz=0.f;

    const int pbeg = offs[n], pend = offs[n + 1];

    float4 dp_cur = make_float4(0.f, 0.f, 0.f, 1.f);
    float  t2cur  = 0.f;
    int    zn_n   = 0;
    if (pbeg < pend) {
        dp_cur = dpack[pbeg];
        t2cur  = T2[znl[pbeg] * HH + h];
        if (pbeg + 1 < pend) zn_n = znl[pbeg + 1];
    }

    for (int ii = pbeg; ii < pend; ++ii) {
        const float4 dpv = dp_cur;
        const float  t2v = t2cur;
        if (ii + 1 < pend) {
            dp_cur = dpack[ii + 1];
            t2cur  = T2[zn_n * HH + h];
            if (ii + 2 < pend) zn_n = znl[ii + 2];
        }

        float d = dpv.w;
        float inv = 1.0f / d;
        float ux = dpv.x*inv, uy = dpv.y*inv, uz = dpv.z*inv;
        float rc = (d < 0.5f) ? 0.5f * (fcos2pi(d) + 1.0f) : 0.0f;

        if (h < 32) {
            float en = fexp2(NEG_ALPHA_L2 * d);
            float t = en - (RBF_START + RBF_STEP * (float)h);
            rbfh[h] = (_Float16)(fexp2(NEG_BETA_L2 * t * t) * rc);
        }
        __builtin_amdgcn_wave_barrier();

        float g1a = ed1, g2a = ed2, g3a = ed3;
        #pragma unroll
        for (int k = 0; k < 4; ++k) {
            uint4 rb = rbp[k];
            g1a = dot16v(w1r[k], rb, g1a);
            g2a = dot16v(w2r[k], rb, g2a);
            g3a = dot16v(w3r[k], rb, g3a);
        }

        float zc = zA + t2v;
        float Cc = rc * zc;
        float f1 = g1a * Cc;
        float f2 = g2a * Cc * 10.0f;
        float f3 = g3a * Cc * 100.0f;

        Is += f1;
        sx += f2 * ux;  sy += f2 * uy;  sz += f2 * uz;
        float q = (ux*ux + uy*uy + uz*uz) * (1.0f / 3.0f);
        Sxx += f3 * (ux*ux - q);
        Syy += f3 * (uy*uy - q);
        Szz += f3 * (uz*uz - q);
        Sxy += f3 * (ux*uy);
        Sxz += f3 * (ux*uz);
        Syz += f3 * (uy*uz);
        __builtin_amdgcn_wave_barrier();
    }

    // tn + LayerNorm (f32, before any fp16 rounding)
    float tn = 3.0f*Is*Is + 2.0f*(sx*sx + sy*sy + sz*sz)
             + Sxx*Sxx + Syy*Syy + Szz*Szz
             + 2.0f*(Sxy*Sxy + Sxz*Sxz + Syz*Syz);
    float s1 = tn, s2 = tn * tn;
    #pragma unroll
    for (int o = 32; o > 0; o >>= 1) {
        s1 += __shfl_xor(s1, o);
        s2 += __shfl_xor(s2, o);
    }
    float mu  = s1 * (1.0f / 64.0f);
    float var = s2 * (1.0f / 64.0f) - mu * mu;
    float nv  = (tn - mu) * rsqrtf(var + 1e-5f) * (WF + OFF_LNG)[h] + (WF + OFF_LNB)[h];

    // pack 11 vectors (10 accums + nv) to fp16 pairs; even lanes store
    float vals[11] = {Is, sx, sy, sz, Sxx, Syy, Szz, Sxy, Sxz, Syz, nv};
    #pragma unroll
    for (int c = 0; c < 11; ++c) {
        float pv = __shfl_xor(vals[c], 1);
        if ((h & 1) == 0)
            accH[((n * 11 + c) << 5) + (h >> 1)] = packh2(vals[c], pv);
    }
}

// Epilogue: MLP + transform. ls2 fp16 in LDS (stride 68 uints, conflict-free);
// ls1/lt fp16 from global (L1-resident).
// ONLY change vs the 207.1us R1 config: grid 256 -> 500 (was 1 block/CU; LDS
// 52KB permits 3/CU; grid-stride loop unchanged, now ~2/CU -> 2x latency hiding).
__global__ __launch_bounds__(256, 2) void k_post(
    const float* __restrict__ WF,
    const unsigned* __restrict__ PH,
    const unsigned* __restrict__ accH,
    float* __restrict__ out)
{
    __shared__ __align__(16) unsigned wL2[192 * 68];    // 52224 B
    __shared__ __align__(16) unsigned acch[4][12 * 32]; // per-wave: 11 vecs (+pad)
    __shared__ __align__(16) unsigned y1h[4][64];
    __shared__ __align__(16) unsigned y2h[4][96];

    for (int q = threadIdx.x; q < 12288; q += 256) {
        int m = q >> 6, u = q & 63;
        wL2[m * 68 + u] = PH[PH_L2 + q];
    }
    __syncthreads();

    const int wave = threadIdx.x >> 6;
    const int h    = threadIdx.x & 63;
    const int gw   = blockIdx.x * 4 + wave;
    const int GW   = gridDim.x * 4;

    const uint4* l1base = (const uint4*)(PH + PH_L1);
    const uint4* lt0 = (const uint4*)(PH + PH_LT) + h * 8;
    const uint4* lt1 = (const uint4*)(PH + PH_LT + 2048) + h * 8;
    const uint4* lt2 = (const uint4*)(PH + PH_LT + 4096) + h * 8;

    for (int n = gw; n < N_ATOMS; n += GW) {
        // stage this atom's 11 fp16 vectors
        if (h < 32) {
            #pragma unroll
            for (int c = 0; c < 11; ++c)
                acch[wave][c * 32 + h] = accH[((n * 11 + c) << 5) + h];
        }
        __builtin_amdgcn_wave_barrier();

        const uint4* nvh = (const uint4*)&acch[wave][10 * 32];

        // y1 = silu(ls1_w @ nv + b1): j = h, h+64
        float ya = (WF + OFF_L1B)[h];
        float yb = (WF + OFF_L1B)[h + 64];
        {
            const uint4* ra = l1base + h * 8;
            const uint4* rb = l1base + (h + 64) * 8;
            #pragma unroll
            for (int k = 0; k < 8; ++k) {
                ya = dot16h(ra + k, nvh + k, ya);
                yb = dot16h(rb + k, nvh + k, yb);
            }
        }
        ya = fsilu(ya); yb = fsilu(yb);
        {
            float pa = __shfl_xor(ya, 1);
            float pb = __shfl_xor(yb, 1);
            if ((h & 1) == 0) {
                y1h[wave][(h >> 1)]      = packh2(ya, pa);
                y1h[wave][32 + (h >> 1)] = packh2(yb, pb);
            }
        }
        __builtin_amdgcn_wave_barrier();

        // y2 = silu(ls2_w @ y1 + b2): m = h, h+64, h+128
        const uint4* y1p = (const uint4*)&y1h[wave][0];
        float z0 = (WF + OFF_L2B)[h];
        float z1 = (WF + OFF_L2B)[h + 64];
        float z2 = (WF + OFF_L2B)[h + 128];
        {
            const uint4* r0 = (const uint4*)&wL2[(h)       * 68];
            const uint4* r1 = (const uint4*)&wL2[(h + 64)  * 68];
            const uint4* r2 = (const uint4*)&wL2[(h + 128) * 68];
            #pragma unroll
            for (int k = 0; k < 16; ++k) {
                uint4 x = y1p[k];
                uint4 a0 = r0[k], a1 = r1[k], a2 = r2[k];
                z0 = FDOT2(u2h(a0.x), u2h(x.x), z0); z0 = FDOT2(u2h(a0.y), u2h(x.y), z0);
                z0 = FDOT2(u2h(a0.z), u2h(x.z), z0); z0 = FDOT2(u2h(a0.w), u2h(x.w), z0);
                z1 = FDOT2(u2h(a1.x), u2h(x.x), z1); z1 = FDOT2(u2h(a1.y), u2h(x.y), z1);
                z1 = FDOT2(u2h(a1.z), u2h(x.z), z1); z1 = FDOT2(u2h(a1.w), u2h(x.w), z1);
                z2 = FDOT2(u2h(a2.x), u2h(x.x), z2); z2 = FDOT2(u2h(a2.y), u2h(x.y), z2);
                z2 = FDOT2(u2h(a2.z), u2h(x.z), z2); z2 = FDOT2(u2h(a2.w), u2h(x.w), z2);
            }
        }
        z0 = fsilu(z0); z1 = fsilu(z1); z2 = fsilu(z2);
        {
            float p0 = __shfl_xor(z0, 1);
            float p1 = __shfl_xor(z1, 1);
            float p2 = __shfl_xor(z2, 1);
            if ((h & 1) == 0) {
                y2h[wave][(h >> 1)]      = packh2(z0, p0);
                y2h[wave][32 + (h >> 1)] = packh2(z1, p1);
                y2h[wave][64 + (h >> 1)] = packh2(z2, p2);
            }
        }
        __builtin_amdgcn_wave_barrier();

        // norm multipliers n0..n2 = y2[3h..3h+2]
        float n0, n1, n2;
        {
            int i0 = 3 * h;
            unsigned u0 = y2h[wave][i0 >> 1];
            unsigned u1 = y2h[wave][(i0 >> 1) + 1];
            h2_t a = u2h(u0), b = u2h(u1);
            if (i0 & 1) { n0 = (float)a.y; n1 = (float)b.x; n2 = (float)b.y; }
            else        { n0 = (float)a.x; n1 = (float)a.y; n2 = (float)b.x; }
        }

        // transform: 10 dot64 against lt rows
        const uint4* aI  = (const uint4*)&acch[wave][0];
        const uint4* aAx = (const uint4*)&acch[wave][32];
        const uint4* aAy = (const uint4*)&acch[wave][64];
        const uint4* aAz = (const uint4*)&acch[wave][96];
        const uint4* aXX = (const uint4*)&acch[wave][128];
        const uint4* aYY = (const uint4*)&acch[wave][160];
        const uint4* aZZ = (const uint4*)&acch[wave][192];
        const uint4* aXY = (const uint4*)&acch[wave][224];
        const uint4* aXZ = (const uint4*)&acch[wave][256];
        const uint4* aYZ = (const uint4*)&acch[wave][288];

        float P0=0.f, PAx=0.f, PAy=0.f, PAz=0.f;
        float Q0=0.f, Q1=0.f, Q2=0.f, Q3=0.f, Q4=0.f, Q5=0.f;
        #pragma unroll
        for (int k = 0; k < 8; ++k) {
            P0  = dot16h(lt0 + k, aI  + k, P0);
            PAx = dot16h(lt1 + k, aAx + k, PAx);
            PAy = dot16h(lt1 + k, aAy + k, PAy);
            PAz = dot16h(lt1 + k, aAz + k, PAz);
            Q0  = dot16h(lt2 + k, aXX + k, Q0);
            Q1  = dot16h(lt2 + k, aYY + k, Q1);
            Q2  = dot16h(lt2 + k, aZZ + k, Q2);
            Q3  = dot16h(lt2 + k, aXY + k, Q3);
            Q4  = dot16h(lt2 + k, aXZ + k, Q4);
            Q5  = dot16h(lt2 + k, aYZ + k, Q5);
        }
        float Iv = P0 * n0;
        float Ax = PAx * n1, Ay = PAy * n1, Az = PAz * n1;
        float Xx = Q0 * n2, Yy = Q1 * n2, Zz = Q2 * n2;
        float Xy = Q3 * n2, Xz = Q4 * n2, Yz = Q5 * n2;

        float* o = out + (size_t)n * 576 + h * 9;
        o[0] =  Iv + Xx;  o[1] = -Az + Xy;  o[2] =  Ay + Xz;
        o[3] =  Az + Xy;  o[4] =  Iv + Yy;  o[5] = -Ax + Yz;
        o[6] = -Ay + Xz;  o[7] =  Ax + Yz;  o[8] =  Iv + Zz;
        __builtin_amdgcn_wave_barrier();
    }
}

extern "C" void kernel_launch(void* const* d_in, const int* in_sizes, int n_in,
                              void* d_out, int out_size, void* d_ws, size_t ws_size,
                              hipStream_t stream) {
    const int* an   = (const int*)d_in[0];
    const int* pidx = (const int*)d_in[1];

    char* ws = (char*)d_ws;
    float*    WF    = (float*)(ws + WS_WF);
    int*      cnt   = (int*)(ws + WS_CNT);
    int*      offs  = (int*)(ws + WS_OFF);
    int*      cur   = (int*)(ws + WS_CUR);
    float*    T1    = (float*)(ws + WS_T1);
    float*    T2    = (float*)(ws + WS_T2);
    unsigned* PH    = (unsigned*)(ws + WS_PH);
    float4*   dpack = (float4*)(ws + WS_DPK);
    int*      znl   = (int*)(ws + WS_ZNL);
    unsigned* accH  = (unsigned*)(ws + WS_ACCH);
    float*    out   = (float*)d_out;

    hipMemsetAsync(cnt, 0, N_ATOMS * sizeof(int), stream);

    ConvArgs ca;
    for (int i = 0; i < 18; ++i) ca.src[i] = d_in[4 + i];
    ca.dst = WF;
    k_prep<<<(N_PAIRS + 255) / 256, 256, 0, stream>>>(ca, pidx, cnt);
    k_tabpack<<<100, 256, 0, stream>>>(WF, T1, T2, PH);
    k_scan<<<1, 1024, 0, stream>>>(cnt, offs, cur);
    k_fill<<<(N_PAIRS + 255) / 256, 256, 0, stream>>>(pidx, an, d_in[2], d_in[3],
                                                      cur, dpack, znl);
    k_pair<<<2500, 256, 0, stream>>>(an, WF, offs, dpack, znl, T1, T2, PH, accH);
    k_post<<<500, 256, 0, stream>>>(WF, PH, accH, out);
}